// Round 1
// baseline (6999.387 us; speedup 1.0000x reference)
//
#include <hip/hip_runtime.h>
#include <stdint.h>

#define N_NODES 100000
#define F 128
#define E_EDGES 1600000
#define KARY 8
#define NPERMS 4
#define NOUT 64

// ---------------- threefry2x32 (JAX-exact, 20 rounds) ----------------
__device__ __forceinline__ uint32_t rotl32(uint32_t v, int r) {
  return (v << r) | (v >> (32 - r));
}
__device__ __forceinline__ void tf2x32(uint32_t k0, uint32_t k1, uint32_t& x0, uint32_t& x1) {
  uint32_t ks2 = k0 ^ k1 ^ 0x1BD11BDAu;
  x0 += k0; x1 += k1;
  x0 += x1; x1 = rotl32(x1,13); x1 ^= x0;
  x0 += x1; x1 = rotl32(x1,15); x1 ^= x0;
  x0 += x1; x1 = rotl32(x1,26); x1 ^= x0;
  x0 += x1; x1 = rotl32(x1, 6); x1 ^= x0;
  x0 += k1; x1 += ks2 + 1u;
  x0 += x1; x1 = rotl32(x1,17); x1 ^= x0;
  x0 += x1; x1 = rotl32(x1,29); x1 ^= x0;
  x0 += x1; x1 = rotl32(x1,16); x1 ^= x0;
  x0 += x1; x1 = rotl32(x1,24); x1 ^= x0;
  x0 += ks2; x1 += k0 + 2u;
  x0 += x1; x1 = rotl32(x1,13); x1 ^= x0;
  x0 += x1; x1 = rotl32(x1,15); x1 ^= x0;
  x0 += x1; x1 = rotl32(x1,26); x1 ^= x0;
  x0 += x1; x1 = rotl32(x1, 6); x1 ^= x0;
  x0 += k0; x1 += k1 + 3u;
  x0 += x1; x1 = rotl32(x1,17); x1 ^= x0;
  x0 += x1; x1 = rotl32(x1,29); x1 ^= x0;
  x0 += x1; x1 = rotl32(x1,16); x1 ^= x0;
  x0 += x1; x1 = rotl32(x1,24); x1 ^= x0;
  x0 += k1; x1 += ks2 + 4u;
  x0 += x1; x1 = rotl32(x1,13); x1 ^= x0;
  x0 += x1; x1 = rotl32(x1,15); x1 ^= x0;
  x0 += x1; x1 = rotl32(x1,26); x1 ^= x0;
  x0 += x1; x1 = rotl32(x1, 6); x1 ^= x0;
  x0 += ks2; x1 += k0 + 5u;
}

// bf16 helpers (RNE)
__device__ __forceinline__ unsigned short f2bf(float f) {
  uint32_t u = __float_as_uint(f);
  uint32_t r = (u + 0x7FFFu + ((u >> 16) & 1u)) >> 16;
  return (unsigned short)r;
}
__device__ __forceinline__ float bf2f(unsigned short s) {
  return __uint_as_float(((uint32_t)s) << 16);
}
__device__ __forceinline__ float sigmoidf_(float x) {
  return 1.0f / (1.0f + __expf(-x));
}
__device__ __forceinline__ float tanhf_(float x) {
  x = fminf(fmaxf(x, -15.0f), 15.0f);
  float e = __expf(2.0f * x);
  return (e - 1.0f) / (e + 1.0f);
}
__device__ __forceinline__ void fma4(float4& a, float s, const float4& w) {
  a.x = fmaf(s, w.x, a.x); a.y = fmaf(s, w.y, a.y);
  a.z = fmaf(s, w.z, a.z); a.w = fmaf(s, w.w, a.w);
}

// ---------------- CSR build ----------------
__global__ void k_hist(const int2* __restrict__ adj, int* __restrict__ deg) {
  int e = blockIdx.x * blockDim.x + threadIdx.x;
  if (e < E_EDGES) atomicAdd(&deg[adj[e].x], 1);
}

__global__ void k_scan(const int* __restrict__ deg, int* __restrict__ roff) {
  __shared__ int sums[1024];
  const int tid = threadIdx.x;
  const int CH = (N_NODES + 1023) / 1024;  // 98
  int base = tid * CH;
  int s = 0;
  for (int i = 0; i < CH; ++i) {
    int idx = base + i;
    if (idx < N_NODES) s += deg[idx];
  }
  sums[tid] = s;
  __syncthreads();
  for (int off = 1; off < 1024; off <<= 1) {
    int v = (tid >= off) ? sums[tid - off] : 0;
    __syncthreads();
    sums[tid] += v;
    __syncthreads();
  }
  int run = sums[tid] - s;  // exclusive prefix of this thread's chunk
  for (int i = 0; i < CH; ++i) {
    int idx = base + i;
    if (idx < N_NODES) { roff[idx] = run; run += deg[idx]; }
  }
}

__global__ void k_scatter(const int2* __restrict__ adj, const int* __restrict__ roff,
                          int* __restrict__ cursor, int2* __restrict__ csr) {
  int e = blockIdx.x * blockDim.x + threadIdx.x;
  if (e < E_EDGES) {
    int2 a = adj[e];
    int pos = roff[a.x] + atomicAdd(&cursor[a.x], 1);
    csr[pos] = make_int2(a.y, e);  // (dst, edge_id)
  }
}

// ---------------- top-8 neighbor selection (JAX lexsort-exact) ----------------
__global__ void k_select(const int2* __restrict__ csr, const int* __restrict__ roff,
                         const int* __restrict__ deg, int* __restrict__ sel,
                         int* __restrict__ lens) {
  int n = blockIdx.x * blockDim.x + threadIdx.x;
  int p = blockIdx.y;
  if (n >= N_NODES) return;
  // perm key = threefry2x32((0,42), (0,p))  [fold_in]
  uint32_t pk0 = 0u, pk1 = (uint32_t)p;
  tf2x32(0u, 42u, pk0, pk1);
  int off = roff[n], d = deg[n];
  unsigned long long key[KARY];
  int nbr[KARY];
#pragma unroll
  for (int i = 0; i < KARY; ++i) { key[i] = ~0ULL; nbr[i] = -1; }
  for (int e = 0; e < d; ++e) {
    int2 ent = csr[off + e];
    // partitionable 32-bit draw: counter = edge_id (hi=0), bits = y0^y1
    uint32_t x0 = 0u, x1 = (uint32_t)ent.y;
    tf2x32(pk0, pk1, x0, x1);
    uint32_t bits = x0 ^ x1;
    unsigned long long k = ((unsigned long long)(bits >> 9) << 21) | (unsigned)ent.y;
    if (k < key[KARY - 1]) {
      key[KARY - 1] = k; nbr[KARY - 1] = ent.x;
#pragma unroll
      for (int s = KARY - 1; s >= 1; --s) {
        if (key[s] < key[s - 1]) {
          unsigned long long tk = key[s]; key[s] = key[s - 1]; key[s - 1] = tk;
          int tn = nbr[s]; nbr[s] = nbr[s - 1]; nbr[s - 1] = tn;
        }
      }
    }
  }
  int L = d < KARY ? d : KARY;
  if (p == 0) lens[n] = L;
#pragma unroll
  for (int t = 0; t < KARY; ++t)
    sel[((size_t)p * N_NODES + n) * KARY + t] = (t < L) ? nbr[t] : -1;
}

// ---------------- weight prep: transpose + ifgo-interleave ----------------
__global__ void k_prepw(const float* __restrict__ w_ih, const float* __restrict__ w_hh,
                        const float* __restrict__ b_ih, const float* __restrict__ b_hh,
                        float4* __restrict__ wiq, float4* __restrict__ whq,
                        float4* __restrict__ bq) {
  int t = blockIdx.x * blockDim.x + threadIdx.x;
  if (t >= F * F) return;
  int k = t >> 7, fi = t & 127;
  wiq[k * F + fi] = make_float4(w_ih[fi * F + k], w_ih[(F + fi) * F + k],
                                w_ih[(2 * F + fi) * F + k], w_ih[(3 * F + fi) * F + k]);
  whq[k * F + fi] = make_float4(w_hh[fi * F + k], w_hh[(F + fi) * F + k],
                                w_hh[(2 * F + fi) * F + k], w_hh[(3 * F + fi) * F + k]);
  if (k == 0)
    bq[fi] = make_float4(b_ih[fi] + b_hh[fi], b_ih[F + fi] + b_hh[F + fi],
                         b_ih[2 * F + fi] + b_hh[2 * F + fi], b_ih[3 * F + fi] + b_hh[3 * F + fi]);
}

// ---------------- x-side gates: Xgq[n][fi] = (i,f,g,o) bf16 quad ----------------
__global__ __launch_bounds__(256) void k_xg(const float* __restrict__ feat,
                                            const float4* __restrict__ wiq,
                                            const float4* __restrict__ bq,
                                            ushort4* __restrict__ xgq) {
  const int tid = threadIdx.x;
  const int fi = tid & 127, sub = tid >> 7;
  const int nb = blockIdx.x * 8;
  float4 acc[4];
  float4 b = bq[fi];
#pragma unroll
  for (int j = 0; j < 4; ++j) acc[j] = b;
  for (int k = 0; k < F; ++k) {
    float4 w = wiq[k * F + fi];
#pragma unroll
    for (int j = 0; j < 4; ++j) {
      float f = feat[(size_t)(nb + sub * 4 + j) * F + k];
      fma4(acc[j], f, w);
    }
  }
#pragma unroll
  for (int j = 0; j < 4; ++j) {
    int n = nb + sub * 4 + j;
    ushort4 r;
    r.x = f2bf(acc[j].x); r.y = f2bf(acc[j].y);
    r.z = f2bf(acc[j].z); r.w = f2bf(acc[j].w);
    xgq[(size_t)n * F + fi] = r;
  }
}

// ---------------- fused LSTM: 8 nodes x 4 perms per block ----------------
#define LB 8
#define MB 32
__global__ __launch_bounds__(256) void k_lstm(const float4* __restrict__ whq,
                                              const ushort4* __restrict__ xgq,
                                              const int* __restrict__ sel,
                                              const int* __restrict__ lens,
                                              float* __restrict__ hneigh) {
  __shared__ __align__(16) float hs[MB][F];  // 16 KB
  __shared__ int sel_l[MB][KARY];
  __shared__ int len_l[LB];
  const int tid = threadIdx.x;
  const int fi = tid & 127;
  const int g = tid >> 7;  // 0..1 : which half of the 32 sequences
  const int nb = blockIdx.x * LB;

  {
    int m = tid >> 3, t = tid & 7;
    int node = nb + (m >> 2), p = m & 3;
    sel_l[m][t] = sel[((size_t)p * N_NODES + node) * KARY + t];
    if (tid < LB) len_l[tid] = lens[nb + tid];
  }
#pragma unroll
  for (int i = 0; i < 16; ++i) hs[g * 16 + i][fi] = 0.f;
  float c[16];
#pragma unroll
  for (int i = 0; i < 16; ++i) c[i] = 0.f;
  __syncthreads();

  for (int t = 0; t < KARY; ++t) {
    float4 acc[16];
#pragma unroll
    for (int i = 0; i < 16; ++i) acc[i] = make_float4(0.f, 0.f, 0.f, 0.f);
    for (int kg = 0; kg < 32; ++kg) {
      float4 w0 = whq[(4 * kg + 0) * F + fi];
      float4 w1 = whq[(4 * kg + 1) * F + fi];
      float4 w2 = whq[(4 * kg + 2) * F + fi];
      float4 w3 = whq[(4 * kg + 3) * F + fi];
#pragma unroll
      for (int m = 0; m < 16; ++m) {
        float4 hv = *(const float4*)&hs[g * 16 + m][4 * kg];  // wave-uniform: LDS broadcast
        fma4(acc[m], hv.x, w0);
        fma4(acc[m], hv.y, w1);
        fma4(acc[m], hv.z, w2);
        fma4(acc[m], hv.w, w3);
      }
    }
    __syncthreads();  // all hs reads done before epilogue writes
#pragma unroll
    for (int m = 0; m < 16; ++m) {
      int mg = g * 16 + m;
      int nloc = mg >> 2;
      if (t < len_l[nloc]) {  // wave-uniform branch
        int v = sel_l[mg][t];
        ushort4 xr = xgq[(size_t)v * F + fi];
        float ix = acc[m].x + bf2f(xr.x);
        float fx = acc[m].y + bf2f(xr.y);
        float gx = acc[m].z + bf2f(xr.z);
        float ox = acc[m].w + bf2f(xr.w);
        float ii = sigmoidf_(ix);
        float ff = sigmoidf_(fx);
        float gg = tanhf_(gx);
        float oo = sigmoidf_(ox);
        float cn = fmaf(ff, c[m], ii * gg);
        c[m] = cn;
        hs[mg][fi] = oo * tanhf_(cn);
      }
    }
    __syncthreads();
  }
  // mean over the 4 perms of each node; single writer per (node, fi)
#pragma unroll
  for (int nb_l = 0; nb_l < 4; ++nb_l) {
    float s = (c[4 * nb_l] + c[4 * nb_l + 1] + c[4 * nb_l + 2] + c[4 * nb_l + 3]) * 0.25f;
    int node = nb + g * 4 + nb_l;
    hneigh[(size_t)node * F + fi] = s;
  }
}

// ---------------- head: sigmoid([feat, hneigh] @ W + b) ----------------
__global__ __launch_bounds__(256) void k_out(const float* __restrict__ feat,
                                             const float* __restrict__ hn,
                                             const float* __restrict__ weight,
                                             const float* __restrict__ bias,
                                             float* __restrict__ out) {
  const int tid = threadIdx.x;
  const int o = tid & 63, j = tid >> 6;
  const int n = blockIdx.x * 4 + j;
  float acc = bias[o];
  for (int k = 0; k < F; ++k)
    acc = fmaf(feat[(size_t)n * F + k], weight[k * NOUT + o], acc);
  for (int k = 0; k < F; ++k)
    acc = fmaf(hn[(size_t)n * F + k], weight[(F + k) * NOUT + o], acc);
  out[(size_t)n * NOUT + o] = sigmoidf_(acc);
}

extern "C" void kernel_launch(void* const* d_in, const int* in_sizes, int n_in,
                              void* d_out, int out_size, void* d_ws, size_t ws_size,
                              hipStream_t stream) {
  const float* feat = (const float*)d_in[0];
  const int2* adj = (const int2*)d_in[1];
  const float* w_ih = (const float*)d_in[2];
  const float* w_hh = (const float*)d_in[3];
  const float* b_ih = (const float*)d_in[4];
  const float* b_hh = (const float*)d_in[5];
  const float* weight = (const float*)d_in[6];
  const float* bias = (const float*)d_in[7];
  float* out = (float*)d_out;

  size_t off = 0;
  auto take = [&](size_t bytes) -> void* {
    void* p = (char*)d_ws + off;
    off += (bytes + 255) & ~(size_t)255;
    return p;
  };
  int* deg = (int*)take((size_t)N_NODES * 4);
  int* roff = (int*)take((size_t)N_NODES * 4);
  int* cursor = (int*)take((size_t)N_NODES * 4);
  int2* csr = (int2*)take((size_t)E_EDGES * 8);
  int* sel = (int*)take((size_t)NPERMS * N_NODES * KARY * 4);
  int* lens = (int*)take((size_t)N_NODES * 4);
  float4* wiq = (float4*)take((size_t)F * F * 16);
  float4* whq = (float4*)take((size_t)F * F * 16);
  float4* bq = (float4*)take((size_t)F * 16);
  ushort4* xgq = (ushort4*)take((size_t)N_NODES * F * 8);
  float* hn = (float*)take((size_t)N_NODES * F * 4);
  (void)ws_size; (void)in_sizes; (void)n_in; (void)out_size;

  hipMemsetAsync(deg, 0, (size_t)N_NODES * 4, stream);
  hipMemsetAsync(cursor, 0, (size_t)N_NODES * 4, stream);

  k_hist<<<(E_EDGES + 255) / 256, 256, 0, stream>>>(adj, deg);
  k_scan<<<1, 1024, 0, stream>>>(deg, roff);
  k_scatter<<<(E_EDGES + 255) / 256, 256, 0, stream>>>(adj, roff, cursor, csr);
  k_prepw<<<(F * F + 255) / 256, 256, 0, stream>>>(w_ih, w_hh, b_ih, b_hh, wiq, whq, bq);
  k_xg<<<N_NODES / 8, 256, 0, stream>>>(feat, wiq, bq, xgq);
  dim3 gsel((N_NODES + 255) / 256, NPERMS);
  k_select<<<gsel, 256, 0, stream>>>(csr, roff, deg, sel, lens);
  k_lstm<<<N_NODES / 8, 256, 0, stream>>>(whq, xgq, sel, lens, hn);
  k_out<<<N_NODES / 4, 256, 0, stream>>>(feat, hn, weight, bias, out);
}

// Round 2
// 3639.847 us; speedup vs baseline: 1.9230x; 1.9230x over previous
//
#include <hip/hip_runtime.h>
#include <stdint.h>

#define N_NODES 100000
#define F 128
#define E_EDGES 1600000
#define KARY 8
#define NPERMS 4
#define NOUT 64

typedef __attribute__((ext_vector_type(8))) short bf16x8;
typedef __attribute__((ext_vector_type(4))) float f32x4;

// ---------------- threefry2x32 (JAX-exact, 20 rounds) ----------------
__device__ __forceinline__ uint32_t rotl32(uint32_t v, int r) {
  return (v << r) | (v >> (32 - r));
}
__device__ __forceinline__ void tf2x32(uint32_t k0, uint32_t k1, uint32_t& x0, uint32_t& x1) {
  uint32_t ks2 = k0 ^ k1 ^ 0x1BD11BDAu;
  x0 += k0; x1 += k1;
  x0 += x1; x1 = rotl32(x1,13); x1 ^= x0;
  x0 += x1; x1 = rotl32(x1,15); x1 ^= x0;
  x0 += x1; x1 = rotl32(x1,26); x1 ^= x0;
  x0 += x1; x1 = rotl32(x1, 6); x1 ^= x0;
  x0 += k1; x1 += ks2 + 1u;
  x0 += x1; x1 = rotl32(x1,17); x1 ^= x0;
  x0 += x1; x1 = rotl32(x1,29); x1 ^= x0;
  x0 += x1; x1 = rotl32(x1,16); x1 ^= x0;
  x0 += x1; x1 = rotl32(x1,24); x1 ^= x0;
  x0 += ks2; x1 += k0 + 2u;
  x0 += x1; x1 = rotl32(x1,13); x1 ^= x0;
  x0 += x1; x1 = rotl32(x1,15); x1 ^= x0;
  x0 += x1; x1 = rotl32(x1,26); x1 ^= x0;
  x0 += x1; x1 = rotl32(x1, 6); x1 ^= x0;
  x0 += k0; x1 += k1 + 3u;
  x0 += x1; x1 = rotl32(x1,17); x1 ^= x0;
  x0 += x1; x1 = rotl32(x1,29); x1 ^= x0;
  x0 += x1; x1 = rotl32(x1,16); x1 ^= x0;
  x0 += x1; x1 = rotl32(x1,24); x1 ^= x0;
  x0 += k1; x1 += ks2 + 4u;
  x0 += x1; x1 = rotl32(x1,13); x1 ^= x0;
  x0 += x1; x1 = rotl32(x1,15); x1 ^= x0;
  x0 += x1; x1 = rotl32(x1,26); x1 ^= x0;
  x0 += x1; x1 = rotl32(x1, 6); x1 ^= x0;
  x0 += ks2; x1 += k0 + 5u;
}

// bf16 helpers (RNE)
__device__ __forceinline__ unsigned short f2bf(float f) {
  uint32_t u = __float_as_uint(f);
  uint32_t r = (u + 0x7FFFu + ((u >> 16) & 1u)) >> 16;
  return (unsigned short)r;
}
__device__ __forceinline__ float bf2f(unsigned short s) {
  return __uint_as_float(((uint32_t)s) << 16);
}
// fast sigmoid/tanh: native v_exp_f32 + raw v_rcp_f32. Saturation is exact:
// exp2(+inf)->inf -> rcp->0; exp2(-inf)->0.  No clamps needed.
__device__ __forceinline__ float sigf(float x) {
  return __builtin_amdgcn_rcpf(1.0f + exp2f(x * -1.44269504f));
}
__device__ __forceinline__ float tanhfast(float x) {
  float e = exp2f(x * 2.88539008f);
  return fmaf(-2.0f, __builtin_amdgcn_rcpf(e + 1.0f), 1.0f);
}
__device__ __forceinline__ float sigmoidf_(float x) {
  return 1.0f / (1.0f + __expf(-x));
}
__device__ __forceinline__ void fma4(float4& a, float s, const float4& w) {
  a.x = fmaf(s, w.x, a.x); a.y = fmaf(s, w.y, a.y);
  a.z = fmaf(s, w.z, a.z); a.w = fmaf(s, w.w, a.w);
}

// ---------------- CSR build ----------------
__global__ void k_hist(const int2* __restrict__ adj, int* __restrict__ deg) {
  int e = blockIdx.x * blockDim.x + threadIdx.x;
  if (e < E_EDGES) atomicAdd(&deg[adj[e].x], 1);
}

__global__ void k_scan(const int* __restrict__ deg, int* __restrict__ roff) {
  __shared__ int sums[1024];
  const int tid = threadIdx.x;
  const int CH = (N_NODES + 1023) / 1024;  // 98
  int base = tid * CH;
  int s = 0;
  for (int i = 0; i < CH; ++i) {
    int idx = base + i;
    if (idx < N_NODES) s += deg[idx];
  }
  sums[tid] = s;
  __syncthreads();
  for (int off = 1; off < 1024; off <<= 1) {
    int v = (tid >= off) ? sums[tid - off] : 0;
    __syncthreads();
    sums[tid] += v;
    __syncthreads();
  }
  int run = sums[tid] - s;
  for (int i = 0; i < CH; ++i) {
    int idx = base + i;
    if (idx < N_NODES) { roff[idx] = run; run += deg[idx]; }
  }
}

__global__ void k_scatter(const int2* __restrict__ adj, const int* __restrict__ roff,
                          int* __restrict__ cursor, int2* __restrict__ csr) {
  int e = blockIdx.x * blockDim.x + threadIdx.x;
  if (e < E_EDGES) {
    int2 a = adj[e];
    int pos = roff[a.x] + atomicAdd(&cursor[a.x], 1);
    csr[pos] = make_int2(a.y, e);  // (dst, edge_id)
  }
}

// ---------------- top-8 neighbor selection (JAX lexsort-exact) ----------------
__global__ void k_select(const int2* __restrict__ csr, const int* __restrict__ roff,
                         const int* __restrict__ deg, int* __restrict__ sel,
                         int* __restrict__ lens) {
  int n = blockIdx.x * blockDim.x + threadIdx.x;
  int p = blockIdx.y;
  if (n >= N_NODES) return;
  uint32_t pk0 = 0u, pk1 = (uint32_t)p;
  tf2x32(0u, 42u, pk0, pk1);
  int off = roff[n], d = deg[n];
  unsigned long long key[KARY];
  int nbr[KARY];
#pragma unroll
  for (int i = 0; i < KARY; ++i) { key[i] = ~0ULL; nbr[i] = -1; }
  for (int e = 0; e < d; ++e) {
    int2 ent = csr[off + e];
    uint32_t x0 = 0u, x1 = (uint32_t)ent.y;
    tf2x32(pk0, pk1, x0, x1);
    uint32_t bits = x0 ^ x1;
    unsigned long long k = ((unsigned long long)(bits >> 9) << 21) | (unsigned)ent.y;
    if (k < key[KARY - 1]) {
      key[KARY - 1] = k; nbr[KARY - 1] = ent.x;
#pragma unroll
      for (int s = KARY - 1; s >= 1; --s) {
        if (key[s] < key[s - 1]) {
          unsigned long long tk = key[s]; key[s] = key[s - 1]; key[s - 1] = tk;
          int tn = nbr[s]; nbr[s] = nbr[s - 1]; nbr[s - 1] = tn;
        }
      }
    }
  }
  int L = d < KARY ? d : KARY;
  if (p == 0) lens[n] = L;
#pragma unroll
  for (int t = 0; t < KARY; ++t)
    sel[((size_t)p * N_NODES + n) * KARY + t] = (t < L) ? nbr[t] : -1;
}

// ---------------- weight prep ----------------
// whb: bf16 cast of w_hh, row-major [512][128]  (n = gate*128+fi, k)
// wiq: w_ih^T interleaved float4 (i,f,g,o) for k_xg;  bq: bias quads
__global__ void k_prepw(const float* __restrict__ w_ih, const float* __restrict__ w_hh,
                        const float* __restrict__ b_ih, const float* __restrict__ b_hh,
                        float4* __restrict__ wiq, float4* __restrict__ bq,
                        short* __restrict__ whb) {
  int t = blockIdx.x * blockDim.x + threadIdx.x;  // 0 .. 4*F*F-1
  if (t >= 4 * F * F) return;
  whb[t] = (short)f2bf(w_hh[t]);
  if (t < F * F) {
    int k = t >> 7, fi = t & 127;
    wiq[k * F + fi] = make_float4(w_ih[fi * F + k], w_ih[(F + fi) * F + k],
                                  w_ih[(2 * F + fi) * F + k], w_ih[(3 * F + fi) * F + k]);
    if (k == 0)
      bq[fi] = make_float4(b_ih[fi] + b_hh[fi], b_ih[F + fi] + b_hh[F + fi],
                           b_ih[2 * F + fi] + b_hh[2 * F + fi], b_ih[3 * F + fi] + b_hh[3 * F + fi]);
  }
}

// ---------------- x-side gates: Xgq[n][fi] = (i,f,g,o) bf16 quad ----------------
__global__ __launch_bounds__(256) void k_xg(const float* __restrict__ feat,
                                            const float4* __restrict__ wiq,
                                            const float4* __restrict__ bq,
                                            ushort4* __restrict__ xgq) {
  const int tid = threadIdx.x;
  const int fi = tid & 127, sub = tid >> 7;
  const int nb = blockIdx.x * 8;
  float4 acc[4];
  float4 b = bq[fi];
#pragma unroll
  for (int j = 0; j < 4; ++j) acc[j] = b;
  for (int k = 0; k < F; ++k) {
    float4 w = wiq[k * F + fi];
#pragma unroll
    for (int j = 0; j < 4; ++j) {
      float f = feat[(size_t)(nb + sub * 4 + j) * F + k];
      fma4(acc[j], f, w);
    }
  }
#pragma unroll
  for (int j = 0; j < 4; ++j) {
    int n = nb + sub * 4 + j;
    ushort4 r;
    r.x = f2bf(acc[j].x); r.y = f2bf(acc[j].y);
    r.z = f2bf(acc[j].z); r.w = f2bf(acc[j].w);
    xgq[(size_t)n * F + fi] = r;
  }
}

// ---------------- fused LSTM via MFMA: 8 nodes x 4 perms per block ----------------
// M=32 sequences, N=512 gates (gate-major), K=128.  4 waves; wave w owns
// fi in [32w, 32w+32).  16 acc tiles/wave = (mt 2) x (ft 2) x (gate 4).
// h round-trips LDS in bf16; c stays fp32 in registers (C-layout).
#define LB 8
#define HS_LD 136  // 128 + 8 pad (keeps 16B align, breaks bank stride)
__global__ __launch_bounds__(256, 3) void k_lstm(const short* __restrict__ whb,
                                                 const ushort4* __restrict__ xgq,
                                                 const int* __restrict__ sel,
                                                 const int* __restrict__ lens,
                                                 float* __restrict__ hneigh) {
  __shared__ short hs[32 * HS_LD];   // 8704 B
  __shared__ int sel_l[32][9];       // padded: q-groups hit distinct banks
  const int tid = threadIdx.x;
  const int w = tid >> 6;
  const int l = tid & 63;
  const int l15 = l & 15, q = l >> 4;
  const int nb = blockIdx.x * LB;

  {
    int m = tid >> 3, t = tid & 7;
    int node = nb + (m >> 2), p = m & 3;
    sel_l[m][t] = sel[((size_t)p * N_NODES + node) * KARY + t];
  }
  {
    int* h32 = (int*)hs;
    for (int i = tid; i < 32 * HS_LD / 2; i += 256) h32[i] = 0;
  }
  uint32_t lp = 0;
#pragma unroll
  for (int i = 0; i < 8; ++i) lp |= (uint32_t)lens[nb + i] << (4 * i);

  // B-fragment base pointers: lane holds B[k=q*8+j][n = g*128 + 16*ft + 32w + l15]
  const short* bp[4][2];
#pragma unroll
  for (int g4 = 0; g4 < 4; ++g4)
#pragma unroll
    for (int ft = 0; ft < 2; ++ft)
      bp[g4][ft] = whb + (size_t)(g4 * 128 + 16 * ft + 32 * w + l15) * F + q * 8;

  const short* abase = hs + l15 * HS_LD + q * 8;  // A[m=l15][k=q*8+j]

  f32x4 cst[2][2];
#pragma unroll
  for (int mt = 0; mt < 2; ++mt)
#pragma unroll
    for (int ft = 0; ft < 2; ++ft) cst[mt][ft] = (f32x4){0.f, 0.f, 0.f, 0.f};

  __syncthreads();

  for (int t = 0; t < KARY; ++t) {
    f32x4 acc[2][2][4];
#pragma unroll
    for (int mt = 0; mt < 2; ++mt)
#pragma unroll
      for (int ft = 0; ft < 2; ++ft)
#pragma unroll
        for (int g4 = 0; g4 < 4; ++g4) acc[mt][ft][g4] = (f32x4){0.f, 0.f, 0.f, 0.f};

#pragma unroll
    for (int kt = 0; kt < 4; ++kt) {
      bf16x8 a0 = *(const bf16x8*)(abase + 0 * 16 * HS_LD + kt * 32);
      bf16x8 a1 = *(const bf16x8*)(abase + 1 * 16 * HS_LD + kt * 32);
#pragma unroll
      for (int g4 = 0; g4 < 4; ++g4)
#pragma unroll
        for (int ft = 0; ft < 2; ++ft) {
          bf16x8 b = *(const bf16x8*)(bp[g4][ft] + kt * 32);
          acc[0][ft][g4] = __builtin_amdgcn_mfma_f32_16x16x32_bf16(a0, b, acc[0][ft][g4], 0, 0, 0);
          acc[1][ft][g4] = __builtin_amdgcn_mfma_f32_16x16x32_bf16(a1, b, acc[1][ft][g4], 0, 0, 0);
        }
    }
    __syncthreads();  // all hs reads done before epilogue writes

#pragma unroll
    for (int mt = 0; mt < 2; ++mt) {
      int nodeloc = mt * 4 + q;  // C-layout: row = q*4+r (+16*mt); node = row>>2
      int len = (lp >> (4 * nodeloc)) & 15;
      if (t < len) {  // uniform per 16-lane group
#pragma unroll
        for (int r = 0; r < 4; ++r) {
          int seq = mt * 16 + q * 4 + r;
          int v = sel_l[seq][t];
#pragma unroll
          for (int ft = 0; ft < 2; ++ft) {
            int fi = 32 * w + 16 * ft + l15;
            ushort4 xr = xgq[(size_t)v * F + fi];
            float ix = acc[mt][ft][0][r] + bf2f(xr.x);
            float fx = acc[mt][ft][1][r] + bf2f(xr.y);
            float gx = acc[mt][ft][2][r] + bf2f(xr.z);
            float ox = acc[mt][ft][3][r] + bf2f(xr.w);
            float ii = sigf(ix);
            float ff = sigf(fx);
            float gg = tanhfast(gx);
            float oo = sigf(ox);
            float cn = fmaf(ff, cst[mt][ft][r], ii * gg);
            cst[mt][ft][r] = cn;
            float hh = oo * tanhfast(cn);
            hs[seq * HS_LD + fi] = (short)f2bf(hh);
          }
        }
      }
    }
    __syncthreads();
  }

  // mean over the 4 perms (= reg index r) of each node
#pragma unroll
  for (int mt = 0; mt < 2; ++mt) {
    int node = nb + mt * 4 + q;
#pragma unroll
    for (int ft = 0; ft < 2; ++ft) {
      int fi = 32 * w + 16 * ft + l15;
      f32x4 cc = cst[mt][ft];
      hneigh[(size_t)node * F + fi] = (cc.x + cc.y + cc.z + cc.w) * 0.25f;
    }
  }
}

// ---------------- head: sigmoid([feat, hneigh] @ W + b) ----------------
__global__ __launch_bounds__(256) void k_out(const float* __restrict__ feat,
                                             const float* __restrict__ hn,
                                             const float* __restrict__ weight,
                                             const float* __restrict__ bias,
                                             float* __restrict__ out) {
  const int tid = threadIdx.x;
  const int o = tid & 63, j = tid >> 6;
  const int n = blockIdx.x * 4 + j;
  float acc = bias[o];
  for (int k = 0; k < F; ++k)
    acc = fmaf(feat[(size_t)n * F + k], weight[k * NOUT + o], acc);
  for (int k = 0; k < F; ++k)
    acc = fmaf(hn[(size_t)n * F + k], weight[(F + k) * NOUT + o], acc);
  out[(size_t)n * NOUT + o] = sigmoidf_(acc);
}

extern "C" void kernel_launch(void* const* d_in, const int* in_sizes, int n_in,
                              void* d_out, int out_size, void* d_ws, size_t ws_size,
                              hipStream_t stream) {
  const float* feat = (const float*)d_in[0];
  const int2* adj = (const int2*)d_in[1];
  const float* w_ih = (const float*)d_in[2];
  const float* w_hh = (const float*)d_in[3];
  const float* b_ih = (const float*)d_in[4];
  const float* b_hh = (const float*)d_in[5];
  const float* weight = (const float*)d_in[6];
  const float* bias = (const float*)d_in[7];
  float* out = (float*)d_out;

  size_t off = 0;
  auto take = [&](size_t bytes) -> void* {
    void* p = (char*)d_ws + off;
    off += (bytes + 255) & ~(size_t)255;
    return p;
  };
  int* deg = (int*)take((size_t)N_NODES * 4);
  int* roff = (int*)take((size_t)N_NODES * 4);
  int* cursor = (int*)take((size_t)N_NODES * 4);
  int2* csr = (int2*)take((size_t)E_EDGES * 8);
  int* sel = (int*)take((size_t)NPERMS * N_NODES * KARY * 4);
  int* lens = (int*)take((size_t)N_NODES * 4);
  float4* wiq = (float4*)take((size_t)F * F * 16);
  float4* bq = (float4*)take((size_t)F * 16);
  short* whb = (short*)take((size_t)4 * F * F * 2);
  ushort4* xgq = (ushort4*)take((size_t)N_NODES * F * 8);
  float* hn = (float*)take((size_t)N_NODES * F * 4);
  (void)ws_size; (void)in_sizes; (void)n_in; (void)out_size;

  hipMemsetAsync(deg, 0, (size_t)N_NODES * 4, stream);
  hipMemsetAsync(cursor, 0, (size_t)N_NODES * 4, stream);

  k_hist<<<(E_EDGES + 255) / 256, 256, 0, stream>>>(adj, deg);
  k_scan<<<1, 1024, 0, stream>>>(deg, roff);
  k_scatter<<<(E_EDGES + 255) / 256, 256, 0, stream>>>(adj, roff, cursor, csr);
  k_prepw<<<(4 * F * F + 255) / 256, 256, 0, stream>>>(w_ih, w_hh, b_ih, b_hh, wiq, bq, whb);
  k_xg<<<N_NODES / 8, 256, 0, stream>>>(feat, wiq, bq, xgq);
  dim3 gsel((N_NODES + 255) / 256, NPERMS);
  k_select<<<gsel, 256, 0, stream>>>(csr, roff, deg, sel, lens);
  k_lstm<<<N_NODES / 8, 256, 0, stream>>>(whb, xgq, sel, lens, hn);
  k_out<<<N_NODES / 4, 256, 0, stream>>>(feat, hn, weight, bias, out);
}

// Round 3
// 1857.474 us; speedup vs baseline: 3.7682x; 1.9596x over previous
//
#include <hip/hip_runtime.h>
#include <stdint.h>

#define N_NODES 100000
#define F 128
#define E_EDGES 1600000
#define KARY 8
#define NPERMS 4
#define NOUT 64

typedef __attribute__((ext_vector_type(8))) short bf16x8;
typedef __attribute__((ext_vector_type(4))) float f32x4;

// ---------------- threefry2x32 (JAX-exact, 20 rounds) ----------------
__device__ __forceinline__ uint32_t rotl32(uint32_t v, int r) {
  return (v << r) | (v >> (32 - r));
}
__device__ __forceinline__ void tf2x32(uint32_t k0, uint32_t k1, uint32_t& x0, uint32_t& x1) {
  uint32_t ks2 = k0 ^ k1 ^ 0x1BD11BDAu;
  x0 += k0; x1 += k1;
  x0 += x1; x1 = rotl32(x1,13); x1 ^= x0;
  x0 += x1; x1 = rotl32(x1,15); x1 ^= x0;
  x0 += x1; x1 = rotl32(x1,26); x1 ^= x0;
  x0 += x1; x1 = rotl32(x1, 6); x1 ^= x0;
  x0 += k1; x1 += ks2 + 1u;
  x0 += x1; x1 = rotl32(x1,17); x1 ^= x0;
  x0 += x1; x1 = rotl32(x1,29); x1 ^= x0;
  x0 += x1; x1 = rotl32(x1,16); x1 ^= x0;
  x0 += x1; x1 = rotl32(x1,24); x1 ^= x0;
  x0 += ks2; x1 += k0 + 2u;
  x0 += x1; x1 = rotl32(x1,13); x1 ^= x0;
  x0 += x1; x1 = rotl32(x1,15); x1 ^= x0;
  x0 += x1; x1 = rotl32(x1,26); x1 ^= x0;
  x0 += x1; x1 = rotl32(x1, 6); x1 ^= x0;
  x0 += k0; x1 += k1 + 3u;
  x0 += x1; x1 = rotl32(x1,17); x1 ^= x0;
  x0 += x1; x1 = rotl32(x1,29); x1 ^= x0;
  x0 += x1; x1 = rotl32(x1,16); x1 ^= x0;
  x0 += x1; x1 = rotl32(x1,24); x1 ^= x0;
  x0 += k1; x1 += ks2 + 4u;
  x0 += x1; x1 = rotl32(x1,13); x1 ^= x0;
  x0 += x1; x1 = rotl32(x1,15); x1 ^= x0;
  x0 += x1; x1 = rotl32(x1,26); x1 ^= x0;
  x0 += x1; x1 = rotl32(x1, 6); x1 ^= x0;
  x0 += ks2; x1 += k0 + 5u;
}

// bf16 helpers (RNE)
__device__ __forceinline__ unsigned short f2bf(float f) {
  uint32_t u = __float_as_uint(f);
  uint32_t r = (u + 0x7FFFu + ((u >> 16) & 1u)) >> 16;
  return (unsigned short)r;
}
__device__ __forceinline__ float bf2f(unsigned short s) {
  return __uint_as_float(((uint32_t)s) << 16);
}
__device__ __forceinline__ float sigf(float x) {
  return __builtin_amdgcn_rcpf(1.0f + exp2f(x * -1.44269504f));
}
__device__ __forceinline__ float tanhfast(float x) {
  float e = exp2f(x * 2.88539008f);
  return fmaf(-2.0f, __builtin_amdgcn_rcpf(e + 1.0f), 1.0f);
}
__device__ __forceinline__ float sigmoidf_(float x) {
  return 1.0f / (1.0f + __expf(-x));
}

// ---------------- CSR build ----------------
__global__ void k_hist(const int2* __restrict__ adj, int* __restrict__ deg) {
  int e = blockIdx.x * blockDim.x + threadIdx.x;
  if (e < E_EDGES) atomicAdd(&deg[adj[e].x], 1);
}

__global__ void k_scan(const int* __restrict__ deg, int* __restrict__ roff) {
  __shared__ int sums[1024];
  const int tid = threadIdx.x;
  const int CH = (N_NODES + 1023) / 1024;  // 98
  int base = tid * CH;
  int s = 0;
  for (int i = 0; i < CH; ++i) {
    int idx = base + i;
    if (idx < N_NODES) s += deg[idx];
  }
  sums[tid] = s;
  __syncthreads();
  for (int off = 1; off < 1024; off <<= 1) {
    int v = (tid >= off) ? sums[tid - off] : 0;
    __syncthreads();
    sums[tid] += v;
    __syncthreads();
  }
  int run = sums[tid] - s;
  for (int i = 0; i < CH; ++i) {
    int idx = base + i;
    if (idx < N_NODES) { roff[idx] = run; run += deg[idx]; }
  }
}

__global__ void k_scatter(const int2* __restrict__ adj, const int* __restrict__ roff,
                          int* __restrict__ cursor, int2* __restrict__ csr) {
  int e = blockIdx.x * blockDim.x + threadIdx.x;
  if (e < E_EDGES) {
    int2 a = adj[e];
    int pos = roff[a.x] + atomicAdd(&cursor[a.x], 1);
    csr[pos] = make_int2(a.y, e);  // (dst, edge_id)
  }
}

// ---------------- top-8 neighbor selection (JAX lexsort-exact) ----------------
__global__ void k_select(const int2* __restrict__ csr, const int* __restrict__ roff,
                         const int* __restrict__ deg, int* __restrict__ sel,
                         int* __restrict__ lens) {
  int n = blockIdx.x * blockDim.x + threadIdx.x;
  int p = blockIdx.y;
  if (n >= N_NODES) return;
  uint32_t pk0 = 0u, pk1 = (uint32_t)p;
  tf2x32(0u, 42u, pk0, pk1);
  int off = roff[n], d = deg[n];
  unsigned long long key[KARY];
  int nbr[KARY];
#pragma unroll
  for (int i = 0; i < KARY; ++i) { key[i] = ~0ULL; nbr[i] = -1; }
  for (int e = 0; e < d; ++e) {
    int2 ent = csr[off + e];
    uint32_t x0 = 0u, x1 = (uint32_t)ent.y;
    tf2x32(pk0, pk1, x0, x1);
    uint32_t bits = x0 ^ x1;
    unsigned long long k = ((unsigned long long)(bits >> 9) << 21) | (unsigned)ent.y;
    if (k < key[KARY - 1]) {
      key[KARY - 1] = k; nbr[KARY - 1] = ent.x;
#pragma unroll
      for (int s = KARY - 1; s >= 1; --s) {
        if (key[s] < key[s - 1]) {
          unsigned long long tk = key[s]; key[s] = key[s - 1]; key[s - 1] = tk;
          int tn = nbr[s]; nbr[s] = nbr[s - 1]; nbr[s - 1] = tn;
        }
      }
    }
  }
  int L = d < KARY ? d : KARY;
  if (p == 0) lens[n] = L;
#pragma unroll
  for (int t = 0; t < KARY; ++t)
    sel[((size_t)p * N_NODES + n) * KARY + t] = (t < L) ? nbr[t] : -1;
}

// ---------------- weight prep (all bf16 casts + bias quads) ----------------
// wihb/whb: bf16 casts of w_ih / w_hh, gate-major rows [512][128]
// wobT: bf16 transpose of head weight -> [64][256]
// bq: float4 (i,f,g,o) of b_ih+b_hh per fi
__global__ void k_prepw(const float* __restrict__ w_ih, const float* __restrict__ w_hh,
                        const float* __restrict__ b_ih, const float* __restrict__ b_hh,
                        const float* __restrict__ weight,
                        short* __restrict__ wihb, short* __restrict__ whb,
                        short* __restrict__ wobT, float4* __restrict__ bq) {
  int t = blockIdx.x * blockDim.x + threadIdx.x;  // 0 .. 65535
  wihb[t] = (short)f2bf(w_ih[t]);
  whb[t] = (short)f2bf(w_hh[t]);
  if (t < 2 * F * NOUT) {
    int n = t & 63, k = t >> 6;
    wobT[n * 256 + k] = (short)f2bf(weight[k * NOUT + n]);
  }
  if (t < F)
    bq[t] = make_float4(b_ih[t] + b_hh[t], b_ih[F + t] + b_hh[F + t],
                        b_ih[2 * F + t] + b_hh[2 * F + t], b_ih[3 * F + t] + b_hh[3 * F + t]);
}

#define HS_LD 136  // 128 + 8 pad shorts

// ---------------- x-side gates via MFMA: 32 nodes/block ----------------
// Xgq[n][fi] = (i,f,g,o) bf16 quad; gate quad lands in one lane across the
// 4 gate accumulators (C-layout), so the pack is register-local.
__global__ __launch_bounds__(256) void k_xg(const float* __restrict__ feat,
                                            const short* __restrict__ wihb,
                                            const float4* __restrict__ bq,
                                            ushort4* __restrict__ xgq) {
  __shared__ short as_[32 * HS_LD];
  const int tid = threadIdx.x;
  const int w = tid >> 6, l = tid & 63;
  const int l15 = l & 15, q = l >> 4;
  const int nb = blockIdx.x * 32;
#pragma unroll
  for (int i = 0; i < 4; ++i) {
    int idx = tid + i * 256;  // 1024 float4 = 32 rows x 128 cols
    int row = idx >> 5, c4 = (idx & 31) * 4;
    float4 v = *(const float4*)&feat[(size_t)(nb + row) * F + c4];
    ushort4 s;
    s.x = f2bf(v.x); s.y = f2bf(v.y); s.z = f2bf(v.z); s.w = f2bf(v.w);
    *(ushort4*)&as_[row * HS_LD + c4] = s;
  }
  __syncthreads();

  f32x4 acc[2][2][4];
#pragma unroll
  for (int mt = 0; mt < 2; ++mt)
#pragma unroll
    for (int ft = 0; ft < 2; ++ft)
#pragma unroll
      for (int g4 = 0; g4 < 4; ++g4) acc[mt][ft][g4] = (f32x4){0.f, 0.f, 0.f, 0.f};

  const short* ab = as_ + l15 * HS_LD + q * 8;
#pragma unroll
  for (int kt = 0; kt < 4; ++kt) {
    bf16x8 a0 = *(const bf16x8*)(ab + kt * 32);
    bf16x8 a1 = *(const bf16x8*)(ab + 16 * HS_LD + kt * 32);
#pragma unroll
    for (int g4 = 0; g4 < 4; ++g4)
#pragma unroll
      for (int ft = 0; ft < 2; ++ft) {
        bf16x8 b = *(const bf16x8*)(wihb + (size_t)(g4 * 128 + 16 * ft + 32 * w + l15) * F + q * 8 + kt * 32);
        acc[0][ft][g4] = __builtin_amdgcn_mfma_f32_16x16x32_bf16(a0, b, acc[0][ft][g4], 0, 0, 0);
        acc[1][ft][g4] = __builtin_amdgcn_mfma_f32_16x16x32_bf16(a1, b, acc[1][ft][g4], 0, 0, 0);
      }
  }
#pragma unroll
  for (int mt = 0; mt < 2; ++mt)
#pragma unroll
    for (int ft = 0; ft < 2; ++ft) {
      int fi = 32 * w + 16 * ft + l15;
      float4 bb = bq[fi];
#pragma unroll
      for (int r = 0; r < 4; ++r) {
        int node = nb + mt * 16 + q * 4 + r;
        ushort4 o;
        o.x = f2bf(acc[mt][ft][0][r] + bb.x);
        o.y = f2bf(acc[mt][ft][1][r] + bb.y);
        o.z = f2bf(acc[mt][ft][2][r] + bb.z);
        o.w = f2bf(acc[mt][ft][3][r] + bb.w);
        xgq[(size_t)node * F + fi] = o;
      }
    }
}

// ---------------- fused LSTM via MFMA, B register-persistent ----------------
// M=32 seqs (8 nodes x 4 perms), N=512 gates, K=128. Wave w owns fi slice
// [32w,32w+32); its whole B slice (32 bf16x8 = 128 VGPRs) is loaded ONCE.
#define LB 8
__global__ __launch_bounds__(256, 2) void k_lstm(const short* __restrict__ whb,
                                                 const ushort4* __restrict__ xgq,
                                                 const int* __restrict__ sel,
                                                 const int* __restrict__ lens,
                                                 float* __restrict__ hneigh) {
  __shared__ short hs[32 * HS_LD];   // 8704 B
  __shared__ int sel_l[32][9];
  const int tid = threadIdx.x;
  const int w = tid >> 6;
  const int l = tid & 63;
  const int l15 = l & 15, q = l >> 4;
  const int nb = blockIdx.x * LB;

  {
    int m = tid >> 3, t = tid & 7;
    int node = nb + (m >> 2), p = m & 3;
    sel_l[m][t] = sel[((size_t)p * N_NODES + node) * KARY + t];
  }
  {
    int* h32 = (int*)hs;
    for (int i = tid; i < 32 * HS_LD / 2; i += 256) h32[i] = 0;
  }
  uint32_t lp = 0;
#pragma unroll
  for (int i = 0; i < 8; ++i) lp |= (uint32_t)lens[nb + i] << (4 * i);

  // persistent B: breg[kt][g4][ft]
  bf16x8 breg[4][4][2];
#pragma unroll
  for (int kt = 0; kt < 4; ++kt)
#pragma unroll
    for (int g4 = 0; g4 < 4; ++g4)
#pragma unroll
      for (int ft = 0; ft < 2; ++ft)
        breg[kt][g4][ft] = *(const bf16x8*)(whb + (size_t)(g4 * 128 + 16 * ft + 32 * w + l15) * F + q * 8 + kt * 32);

  const short* abase = hs + l15 * HS_LD + q * 8;

  f32x4 cst[2][2];
#pragma unroll
  for (int mt = 0; mt < 2; ++mt)
#pragma unroll
    for (int ft = 0; ft < 2; ++ft) cst[mt][ft] = (f32x4){0.f, 0.f, 0.f, 0.f};

  __syncthreads();

  for (int t = 0; t < KARY; ++t) {
    f32x4 acc[2][2][4];
#pragma unroll
    for (int mt = 0; mt < 2; ++mt)
#pragma unroll
      for (int ft = 0; ft < 2; ++ft)
#pragma unroll
        for (int g4 = 0; g4 < 4; ++g4) acc[mt][ft][g4] = (f32x4){0.f, 0.f, 0.f, 0.f};

#pragma unroll
    for (int kt = 0; kt < 4; ++kt) {
      bf16x8 a0 = *(const bf16x8*)(abase + 0 * 16 * HS_LD + kt * 32);
      bf16x8 a1 = *(const bf16x8*)(abase + 1 * 16 * HS_LD + kt * 32);
#pragma unroll
      for (int g4 = 0; g4 < 4; ++g4)
#pragma unroll
        for (int ft = 0; ft < 2; ++ft) {
          acc[0][ft][g4] = __builtin_amdgcn_mfma_f32_16x16x32_bf16(a0, breg[kt][g4][ft], acc[0][ft][g4], 0, 0, 0);
          acc[1][ft][g4] = __builtin_amdgcn_mfma_f32_16x16x32_bf16(a1, breg[kt][g4][ft], acc[1][ft][g4], 0, 0, 0);
        }
    }
    __syncthreads();  // all hs reads done before epilogue writes

#pragma unroll
    for (int mt = 0; mt < 2; ++mt) {
      int nodeloc = mt * 4 + q;
      int len = (lp >> (4 * nodeloc)) & 15;
      if (t < len) {  // uniform per 16-lane group
#pragma unroll
        for (int r = 0; r < 4; ++r) {
          int seq = mt * 16 + q * 4 + r;
          int v = sel_l[seq][t];
#pragma unroll
          for (int ft = 0; ft < 2; ++ft) {
            int fi = 32 * w + 16 * ft + l15;
            ushort4 xr = xgq[(size_t)v * F + fi];
            float ix = acc[mt][ft][0][r] + bf2f(xr.x);
            float fx = acc[mt][ft][1][r] + bf2f(xr.y);
            float gx = acc[mt][ft][2][r] + bf2f(xr.z);
            float ox = acc[mt][ft][3][r] + bf2f(xr.w);
            float ii = sigf(ix);
            float ff = sigf(fx);
            float gg = tanhfast(gx);
            float oo = sigf(ox);
            float cn = fmaf(ff, cst[mt][ft][r], ii * gg);
            cst[mt][ft][r] = cn;
            float hh = oo * tanhfast(cn);
            hs[seq * HS_LD + fi] = (short)f2bf(hh);
          }
        }
      }
    }
    __syncthreads();
  }

#pragma unroll
  for (int mt = 0; mt < 2; ++mt) {
    int node = nb + mt * 4 + q;
#pragma unroll
    for (int ft = 0; ft < 2; ++ft) {
      int fi = 32 * w + 16 * ft + l15;
      f32x4 cc = cst[mt][ft];
      hneigh[(size_t)node * F + fi] = (cc.x + cc.y + cc.z + cc.w) * 0.25f;
    }
  }
}

// ---------------- head via MFMA: 64 nodes/block, N=64, K=256 ----------------
#define OS_LD 264  // 256 + 8 pad shorts
__global__ __launch_bounds__(256) void k_out(const float* __restrict__ feat,
                                             const float* __restrict__ hn,
                                             const short* __restrict__ wobT,
                                             const float* __restrict__ bias,
                                             float* __restrict__ out) {
  __shared__ short as_[64 * OS_LD];  // 33792 B
  const int tid = threadIdx.x;
  const int w = tid >> 6, l = tid & 63;
  const int l15 = l & 15, q = l >> 4;
  const int nb = blockIdx.x * 64;
#pragma unroll
  for (int i = 0; i < 16; ++i) {
    int idx = tid + i * 256;  // 4096 float4 = 64 rows x 256 cols
    int row = idx >> 6, c4 = (idx & 63) * 4;
    int node = nb + row;
    if (node > N_NODES - 1) node = N_NODES - 1;
    float4 v = (c4 < 128) ? *(const float4*)&feat[(size_t)node * F + c4]
                          : *(const float4*)&hn[(size_t)node * F + (c4 - 128)];
    ushort4 s;
    s.x = f2bf(v.x); s.y = f2bf(v.y); s.z = f2bf(v.z); s.w = f2bf(v.w);
    *(ushort4*)&as_[row * OS_LD + c4] = s;
  }
  __syncthreads();

  f32x4 acc[4];
#pragma unroll
  for (int nt = 0; nt < 4; ++nt) acc[nt] = (f32x4){0.f, 0.f, 0.f, 0.f};

  const short* ab = as_ + (w * 16 + l15) * OS_LD + q * 8;
#pragma unroll
  for (int kt = 0; kt < 8; ++kt) {
    bf16x8 a = *(const bf16x8*)(ab + kt * 32);
#pragma unroll
    for (int nt = 0; nt < 4; ++nt) {
      bf16x8 b = *(const bf16x8*)(wobT + (size_t)(nt * 16 + l15) * 256 + q * 8 + kt * 32);
      acc[nt] = __builtin_amdgcn_mfma_f32_16x16x32_bf16(a, b, acc[nt], 0, 0, 0);
    }
  }
#pragma unroll
  for (int nt = 0; nt < 4; ++nt) {
    int col = nt * 16 + l15;
    float bb = bias[col];
#pragma unroll
    for (int r = 0; r < 4; ++r) {
      int node = nb + w * 16 + q * 4 + r;
      if (node < N_NODES)
        out[(size_t)node * NOUT + col] = sigmoidf_(acc[nt][r] + bb);
    }
  }
}

extern "C" void kernel_launch(void* const* d_in, const int* in_sizes, int n_in,
                              void* d_out, int out_size, void* d_ws, size_t ws_size,
                              hipStream_t stream) {
  const float* feat = (const float*)d_in[0];
  const int2* adj = (const int2*)d_in[1];
  const float* w_ih = (const float*)d_in[2];
  const float* w_hh = (const float*)d_in[3];
  const float* b_ih = (const float*)d_in[4];
  const float* b_hh = (const float*)d_in[5];
  const float* weight = (const float*)d_in[6];
  const float* bias = (const float*)d_in[7];
  float* out = (float*)d_out;

  size_t off = 0;
  auto take = [&](size_t bytes) -> void* {
    void* p = (char*)d_ws + off;
    off += (bytes + 255) & ~(size_t)255;
    return p;
  };
  int* deg = (int*)take((size_t)N_NODES * 4);
  int* roff = (int*)take((size_t)N_NODES * 4);
  int* cursor = (int*)take((size_t)N_NODES * 4);
  int2* csr = (int2*)take((size_t)E_EDGES * 8);
  int* sel = (int*)take((size_t)NPERMS * N_NODES * KARY * 4);
  int* lens = (int*)take((size_t)N_NODES * 4);
  short* wihb = (short*)take((size_t)4 * F * F * 2);
  short* whb = (short*)take((size_t)4 * F * F * 2);
  short* wobT = (short*)take((size_t)NOUT * 2 * F * 2);
  float4* bq = (float4*)take((size_t)F * 16);
  ushort4* xgq = (ushort4*)take((size_t)N_NODES * F * 8);
  float* hn = (float*)take((size_t)N_NODES * F * 4);
  (void)ws_size; (void)in_sizes; (void)n_in; (void)out_size;

  hipMemsetAsync(deg, 0, (size_t)N_NODES * 4, stream);
  hipMemsetAsync(cursor, 0, (size_t)N_NODES * 4, stream);

  k_hist<<<(E_EDGES + 255) / 256, 256, 0, stream>>>(adj, deg);
  k_scan<<<1, 1024, 0, stream>>>(deg, roff);
  k_scatter<<<(E_EDGES + 255) / 256, 256, 0, stream>>>(adj, roff, cursor, csr);
  k_prepw<<<4 * F * F / 256, 256, 0, stream>>>(w_ih, w_hh, b_ih, b_hh, weight, wihb, whb, wobT, bq);
  k_xg<<<N_NODES / 32, 256, 0, stream>>>(feat, wihb, bq, xgq);
  dim3 gsel((N_NODES + 255) / 256, NPERMS);
  k_select<<<gsel, 256, 0, stream>>>(csr, roff, deg, sel, lens);
  k_lstm<<<N_NODES / LB, 256, 0, stream>>>(whb, xgq, sel, lens, hn);
  k_out<<<(N_NODES + 63) / 64, 256, 0, stream>>>(feat, hn, wobT, bias, out);
}

// Round 4
// 1700.621 us; speedup vs baseline: 4.1158x; 1.0922x over previous
//
#include <hip/hip_runtime.h>
#include <stdint.h>

#define N_NODES 100000
#define F 128
#define E_EDGES 1600000
#define KARY 8
#define NPERMS 4
#define NOUT 64

typedef __attribute__((ext_vector_type(8))) short bf16x8;
typedef __attribute__((ext_vector_type(4))) float f32x4;

// ---------------- threefry2x32 (JAX-exact, 20 rounds) ----------------
__device__ __forceinline__ uint32_t rotl32(uint32_t v, int r) {
  return (v << r) | (v >> (32 - r));
}
__device__ __forceinline__ void tf2x32(uint32_t k0, uint32_t k1, uint32_t& x0, uint32_t& x1) {
  uint32_t ks2 = k0 ^ k1 ^ 0x1BD11BDAu;
  x0 += k0; x1 += k1;
  x0 += x1; x1 = rotl32(x1,13); x1 ^= x0;
  x0 += x1; x1 = rotl32(x1,15); x1 ^= x0;
  x0 += x1; x1 = rotl32(x1,26); x1 ^= x0;
  x0 += x1; x1 = rotl32(x1, 6); x1 ^= x0;
  x0 += k1; x1 += ks2 + 1u;
  x0 += x1; x1 = rotl32(x1,17); x1 ^= x0;
  x0 += x1; x1 = rotl32(x1,29); x1 ^= x0;
  x0 += x1; x1 = rotl32(x1,16); x1 ^= x0;
  x0 += x1; x1 = rotl32(x1,24); x1 ^= x0;
  x0 += ks2; x1 += k0 + 2u;
  x0 += x1; x1 = rotl32(x1,13); x1 ^= x0;
  x0 += x1; x1 = rotl32(x1,15); x1 ^= x0;
  x0 += x1; x1 = rotl32(x1,26); x1 ^= x0;
  x0 += x1; x1 = rotl32(x1, 6); x1 ^= x0;
  x0 += k0; x1 += k1 + 3u;
  x0 += x1; x1 = rotl32(x1,17); x1 ^= x0;
  x0 += x1; x1 = rotl32(x1,29); x1 ^= x0;
  x0 += x1; x1 = rotl32(x1,16); x1 ^= x0;
  x0 += x1; x1 = rotl32(x1,24); x1 ^= x0;
  x0 += k1; x1 += ks2 + 4u;
  x0 += x1; x1 = rotl32(x1,13); x1 ^= x0;
  x0 += x1; x1 = rotl32(x1,15); x1 ^= x0;
  x0 += x1; x1 = rotl32(x1,26); x1 ^= x0;
  x0 += x1; x1 = rotl32(x1, 6); x1 ^= x0;
  x0 += ks2; x1 += k0 + 5u;
}

// bf16 helpers (RNE)
__device__ __forceinline__ unsigned short f2bf(float f) {
  uint32_t u = __float_as_uint(f);
  uint32_t r = (u + 0x7FFFu + ((u >> 16) & 1u)) >> 16;
  return (unsigned short)r;
}
__device__ __forceinline__ float sigf(float x) {
  return __builtin_amdgcn_rcpf(1.0f + exp2f(x * -1.44269504f));
}
__device__ __forceinline__ float tanhfast(float x) {
  float e = exp2f(x * 2.88539008f);
  return fmaf(-2.0f, __builtin_amdgcn_rcpf(e + 1.0f), 1.0f);
}
__device__ __forceinline__ float sigmoidf_(float x) {
  return 1.0f / (1.0f + __expf(-x));
}

// ---------------- CSR build ----------------
__global__ void k_hist(const int2* __restrict__ adj, int* __restrict__ deg) {
  int e = blockIdx.x * blockDim.x + threadIdx.x;
  if (e < E_EDGES) atomicAdd(&deg[adj[e].x], 1);
}

__global__ void k_scan(const int* __restrict__ deg, int* __restrict__ roff) {
  __shared__ int sums[1024];
  const int tid = threadIdx.x;
  const int CH = (N_NODES + 1023) / 1024;  // 98
  int base = tid * CH;
  int s = 0;
  for (int i = 0; i < CH; ++i) {
    int idx = base + i;
    if (idx < N_NODES) s += deg[idx];
  }
  sums[tid] = s;
  __syncthreads();
  for (int off = 1; off < 1024; off <<= 1) {
    int v = (tid >= off) ? sums[tid - off] : 0;
    __syncthreads();
    sums[tid] += v;
    __syncthreads();
  }
  int run = sums[tid] - s;
  for (int i = 0; i < CH; ++i) {
    int idx = base + i;
    if (idx < N_NODES) { roff[idx] = run; run += deg[idx]; }
  }
}

__global__ void k_scatter(const int2* __restrict__ adj, const int* __restrict__ roff,
                          int* __restrict__ cursor, int2* __restrict__ csr) {
  int e = blockIdx.x * blockDim.x + threadIdx.x;
  if (e < E_EDGES) {
    int2 a = adj[e];
    int pos = roff[a.x] + atomicAdd(&cursor[a.x], 1);
    csr[pos] = make_int2(a.y, e);  // (dst, edge_id)
  }
}

// ---------------- top-8 selection, 4 perms fused (JAX lexsort-exact) --------
__global__ void k_select(const int2* __restrict__ csr, const int* __restrict__ roff,
                         const int* __restrict__ deg, int* __restrict__ sel,
                         int* __restrict__ lens) {
  int n = blockIdx.x * blockDim.x + threadIdx.x;
  if (n >= N_NODES) return;
  uint32_t pk0[NPERMS], pk1[NPERMS];
#pragma unroll
  for (int p = 0; p < NPERMS; ++p) {
    uint32_t a = 0u, b = (uint32_t)p;
    tf2x32(0u, 42u, a, b);
    pk0[p] = a; pk1[p] = b;
  }
  int off = roff[n], d = deg[n];
  unsigned long long key[NPERMS][KARY];
  int nbr[NPERMS][KARY];
#pragma unroll
  for (int p = 0; p < NPERMS; ++p)
#pragma unroll
    for (int i = 0; i < KARY; ++i) { key[p][i] = ~0ULL; nbr[p][i] = -1; }
  for (int e = 0; e < d; ++e) {
    int2 ent = csr[off + e];
#pragma unroll
    for (int p = 0; p < NPERMS; ++p) {
      uint32_t x0 = 0u, x1 = (uint32_t)ent.y;
      tf2x32(pk0[p], pk1[p], x0, x1);
      uint32_t bits = x0 ^ x1;
      unsigned long long k = ((unsigned long long)(bits >> 9) << 21) | (unsigned)ent.y;
      if (k < key[p][KARY - 1]) {
        key[p][KARY - 1] = k; nbr[p][KARY - 1] = ent.x;
#pragma unroll
        for (int s = KARY - 1; s >= 1; --s) {
          if (key[p][s] < key[p][s - 1]) {
            unsigned long long tk = key[p][s]; key[p][s] = key[p][s - 1]; key[p][s - 1] = tk;
            int tn = nbr[p][s]; nbr[p][s] = nbr[p][s - 1]; nbr[p][s - 1] = tn;
          }
        }
      }
    }
  }
  int L = d < KARY ? d : KARY;
  lens[n] = L;
#pragma unroll
  for (int p = 0; p < NPERMS; ++p)
#pragma unroll
    for (int t = 0; t < KARY; ++t)
      sel[((size_t)p * N_NODES + n) * KARY + t] = (t < L) ? nbr[p][t] : -1;
}

// ---------------- weight prep (all bf16 casts + bias quads) ----------------
__global__ void k_prepw(const float* __restrict__ w_ih, const float* __restrict__ w_hh,
                        const float* __restrict__ b_ih, const float* __restrict__ b_hh,
                        const float* __restrict__ weight,
                        short* __restrict__ wihb, short* __restrict__ whb,
                        short* __restrict__ wobT, float4* __restrict__ bq) {
  int t = blockIdx.x * blockDim.x + threadIdx.x;  // 0 .. 65535
  wihb[t] = (short)f2bf(w_ih[t]);
  whb[t] = (short)f2bf(w_hh[t]);
  if (t < 2 * F * NOUT) {
    int n = t & 63, k = t >> 6;
    wobT[n * 256 + k] = (short)f2bf(weight[k * NOUT + n]);
  }
  if (t < F)
    bq[t] = make_float4(b_ih[t] + b_hh[t], b_ih[F + t] + b_hh[F + t],
                        b_ih[2 * F + t] + b_hh[2 * F + t], b_ih[3 * F + t] + b_hh[3 * F + t]);
}

#define HS_LD 136  // 128 + 8 pad shorts

// ---------------- x-side gates via MFMA: 32 nodes/block ----------------
__global__ __launch_bounds__(256) void k_xg(const float* __restrict__ feat,
                                            const short* __restrict__ wihb,
                                            const float4* __restrict__ bq,
                                            ushort4* __restrict__ xgq) {
  __shared__ short as_[32 * HS_LD];
  const int tid = threadIdx.x;
  const int w = tid >> 6, l = tid & 63;
  const int l15 = l & 15, q = l >> 4;
  const int nb = blockIdx.x * 32;
#pragma unroll
  for (int i = 0; i < 4; ++i) {
    int idx = tid + i * 256;  // 1024 float4 = 32 rows x 128 cols
    int row = idx >> 5, c4 = (idx & 31) * 4;
    float4 v = *(const float4*)&feat[(size_t)(nb + row) * F + c4];
    ushort4 s;
    s.x = f2bf(v.x); s.y = f2bf(v.y); s.z = f2bf(v.z); s.w = f2bf(v.w);
    *(ushort4*)&as_[row * HS_LD + c4] = s;
  }
  __syncthreads();

  f32x4 acc[2][2][4];
#pragma unroll
  for (int mt = 0; mt < 2; ++mt)
#pragma unroll
    for (int ft = 0; ft < 2; ++ft)
#pragma unroll
      for (int g4 = 0; g4 < 4; ++g4) acc[mt][ft][g4] = (f32x4){0.f, 0.f, 0.f, 0.f};

  const short* ab = as_ + l15 * HS_LD + q * 8;
#pragma unroll
  for (int kt = 0; kt < 4; ++kt) {
    bf16x8 a0 = *(const bf16x8*)(ab + kt * 32);
    bf16x8 a1 = *(const bf16x8*)(ab + 16 * HS_LD + kt * 32);
#pragma unroll
    for (int g4 = 0; g4 < 4; ++g4)
#pragma unroll
      for (int ft = 0; ft < 2; ++ft) {
        bf16x8 b = *(const bf16x8*)(wihb + (size_t)(g4 * 128 + 16 * ft + 32 * w + l15) * F + q * 8 + kt * 32);
        acc[0][ft][g4] = __builtin_amdgcn_mfma_f32_16x16x32_bf16(a0, b, acc[0][ft][g4], 0, 0, 0);
        acc[1][ft][g4] = __builtin_amdgcn_mfma_f32_16x16x32_bf16(a1, b, acc[1][ft][g4], 0, 0, 0);
      }
  }
#pragma unroll
  for (int mt = 0; mt < 2; ++mt)
#pragma unroll
    for (int ft = 0; ft < 2; ++ft) {
      int fi = 32 * w + 16 * ft + l15;
      float4 bb = bq[fi];
#pragma unroll
      for (int r = 0; r < 4; ++r) {
        int node = nb + mt * 16 + q * 4 + r;
        ushort4 o;
        o.x = f2bf(acc[mt][ft][0][r] + bb.x);
        o.y = f2bf(acc[mt][ft][1][r] + bb.y);
        o.z = f2bf(acc[mt][ft][2][r] + bb.z);
        o.w = f2bf(acc[mt][ft][3][r] + bb.w);
        xgq[(size_t)node * F + fi] = o;
      }
    }
}

// ---------------- fused LSTM via MFMA, B register-persistent ----------------
// M=32 seqs (8 nodes x 4 perms), N=512 gates, K=128. Wave w owns fi slice
// [32w,32w+32). xg gathers for step t are prefetched BEFORE the MFMA phase
// (indices known from sel_l) so their L2/L3 latency hides under MFMA.
#define LB 8
__global__ __launch_bounds__(256, 2) void k_lstm(const short* __restrict__ whb,
                                                 const ushort4* __restrict__ xgq,
                                                 const int* __restrict__ sel,
                                                 const int* __restrict__ lens,
                                                 float* __restrict__ hneigh) {
  __shared__ short hs[32 * HS_LD];   // 8704 B
  __shared__ int sel_l[32][9];
  const int tid = threadIdx.x;
  const int w = tid >> 6;
  const int l = tid & 63;
  const int l15 = l & 15, q = l >> 4;
  const int nb = blockIdx.x * LB;
  const char* xgb = (const char*)xgq;
  const int fi8 = (32 * w + l15) * 8;  // byte offset of this lane's ft=0 quad

  {
    int m = tid >> 3, t = tid & 7;
    int node = nb + (m >> 2), p = m & 3;
    sel_l[m][t] = sel[((size_t)p * N_NODES + node) * KARY + t];
  }
  {
    int* h32 = (int*)hs;
    for (int i = tid; i < 32 * HS_LD / 2; i += 256) h32[i] = 0;
  }
  uint32_t lp = 0;
#pragma unroll
  for (int i = 0; i < 8; ++i) lp |= (uint32_t)lens[nb + i] << (4 * i);

  // persistent B: breg[kt][g4][ft]  (128 VGPRs)
  bf16x8 breg[4][4][2];
#pragma unroll
  for (int kt = 0; kt < 4; ++kt)
#pragma unroll
    for (int g4 = 0; g4 < 4; ++g4)
#pragma unroll
      for (int ft = 0; ft < 2; ++ft)
        breg[kt][g4][ft] = *(const bf16x8*)(whb + (size_t)(g4 * 128 + 16 * ft + 32 * w + l15) * F + q * 8 + kt * 32);

  const short* abase = hs + l15 * HS_LD + q * 8;

  f32x4 cst[2][2];
#pragma unroll
  for (int mt = 0; mt < 2; ++mt)
#pragma unroll
    for (int ft = 0; ft < 2; ++ft) cst[mt][ft] = (f32x4){0.f, 0.f, 0.f, 0.f};

  __syncthreads();

  for (int t = 0; t < KARY; ++t) {
    // ---- prefetch this step's xg quads; latency hides under the MFMA phase
    uint2 xr[2][4][2];  // [mt][r][ft]: (i|f<<16, g|o<<16)
#pragma unroll
    for (int mt = 0; mt < 2; ++mt)
#pragma unroll
      for (int r = 0; r < 4; ++r) {
        int seq = mt * 16 + q * 4 + r;
        int v = sel_l[seq][t];
        v = v < 0 ? 0 : v;
        int off = (v << 10) + fi8;
        xr[mt][r][0] = *(const uint2*)(xgb + off);
        xr[mt][r][1] = *(const uint2*)(xgb + off + 128);
      }

    // ---- MFMA phase
    f32x4 acc[2][2][4];
#pragma unroll
    for (int mt = 0; mt < 2; ++mt)
#pragma unroll
      for (int ft = 0; ft < 2; ++ft)
#pragma unroll
        for (int g4 = 0; g4 < 4; ++g4) acc[mt][ft][g4] = (f32x4){0.f, 0.f, 0.f, 0.f};

#pragma unroll
    for (int kt = 0; kt < 4; ++kt) {
      bf16x8 a0 = *(const bf16x8*)(abase + 0 * 16 * HS_LD + kt * 32);
      bf16x8 a1 = *(const bf16x8*)(abase + 1 * 16 * HS_LD + kt * 32);
#pragma unroll
      for (int g4 = 0; g4 < 4; ++g4)
#pragma unroll
        for (int ft = 0; ft < 2; ++ft) {
          acc[0][ft][g4] = __builtin_amdgcn_mfma_f32_16x16x32_bf16(a0, breg[kt][g4][ft], acc[0][ft][g4], 0, 0, 0);
          acc[1][ft][g4] = __builtin_amdgcn_mfma_f32_16x16x32_bf16(a1, breg[kt][g4][ft], acc[1][ft][g4], 0, 0, 0);
        }
    }
    __syncthreads();  // all hs reads done before epilogue writes

    // ---- epilogue: gates computed unconditionally; state update masked
#pragma unroll
    for (int mt = 0; mt < 2; ++mt) {
      int len = (lp >> (4 * (mt * 4 + q))) & 15;
      bool live = t < len;
#pragma unroll
      for (int r = 0; r < 4; ++r) {
        int seq = mt * 16 + q * 4 + r;
#pragma unroll
        for (int ft = 0; ft < 2; ++ft) {
          uint2 x = xr[mt][r][ft];
          float ix = acc[mt][ft][0][r] + __uint_as_float(x.x << 16);
          float fx = acc[mt][ft][1][r] + __uint_as_float(x.x & 0xffff0000u);
          float gx = acc[mt][ft][2][r] + __uint_as_float(x.y << 16);
          float ox = acc[mt][ft][3][r] + __uint_as_float(x.y & 0xffff0000u);
          float ii = sigf(ix);
          float ff = sigf(fx);
          float gg = tanhfast(gx);
          float oo = sigf(ox);
          float cn = fmaf(ff, cst[mt][ft][r], ii * gg);
          float hh = oo * tanhfast(cn);
          if (live) {
            cst[mt][ft][r] = cn;
            hs[seq * HS_LD + 32 * w + 16 * ft + l15] = (short)f2bf(hh);
          }
        }
      }
    }
    __syncthreads();
  }

#pragma unroll
  for (int mt = 0; mt < 2; ++mt) {
    int node = nb + mt * 4 + q;
#pragma unroll
    for (int ft = 0; ft < 2; ++ft) {
      int fi = 32 * w + 16 * ft + l15;
      f32x4 cc = cst[mt][ft];
      hneigh[(size_t)node * F + fi] = (cc.x + cc.y + cc.z + cc.w) * 0.25f;
    }
  }
}

// ---------------- head via MFMA: 64 nodes/block, N=64, K=256 ----------------
#define OS_LD 264  // 256 + 8 pad shorts
__global__ __launch_bounds__(256) void k_out(const float* __restrict__ feat,
                                             const float* __restrict__ hn,
                                             const short* __restrict__ wobT,
                                             const float* __restrict__ bias,
                                             float* __restrict__ out) {
  __shared__ short as_[64 * OS_LD];  // 33792 B
  const int tid = threadIdx.x;
  const int w = tid >> 6, l = tid & 63;
  const int l15 = l & 15, q = l >> 4;
  const int nb = blockIdx.x * 64;
#pragma unroll
  for (int i = 0; i < 16; ++i) {
    int idx = tid + i * 256;  // 4096 float4 = 64 rows x 256 cols
    int row = idx >> 6, c4 = (idx & 63) * 4;
    int node = nb + row;
    if (node > N_NODES - 1) node = N_NODES - 1;
    float4 v = (c4 < 128) ? *(const float4*)&feat[(size_t)node * F + c4]
                          : *(const float4*)&hn[(size_t)node * F + (c4 - 128)];
    ushort4 s;
    s.x = f2bf(v.x); s.y = f2bf(v.y); s.z = f2bf(v.z); s.w = f2bf(v.w);
    *(ushort4*)&as_[row * OS_LD + c4] = s;
  }
  __syncthreads();

  f32x4 acc[4];
#pragma unroll
  for (int nt = 0; nt < 4; ++nt) acc[nt] = (f32x4){0.f, 0.f, 0.f, 0.f};

  const short* ab = as_ + (w * 16 + l15) * OS_LD + q * 8;
#pragma unroll
  for (int kt = 0; kt < 8; ++kt) {
    bf16x8 a = *(const bf16x8*)(ab + kt * 32);
#pragma unroll
    for (int nt = 0; nt < 4; ++nt) {
      bf16x8 b = *(const bf16x8*)(wobT + (size_t)(nt * 16 + l15) * 256 + q * 8 + kt * 32);
      acc[nt] = __builtin_amdgcn_mfma_f32_16x16x32_bf16(a, b, acc[nt], 0, 0, 0);
    }
  }
#pragma unroll
  for (int nt = 0; nt < 4; ++nt) {
    int col = nt * 16 + l15;
    float bb = bias[col];
#pragma unroll
    for (int r = 0; r < 4; ++r) {
      int node = nb + w * 16 + q * 4 + r;
      if (node < N_NODES)
        out[(size_t)node * NOUT + col] = sigmoidf_(acc[nt][r] + bb);
    }
  }
}

extern "C" void kernel_launch(void* const* d_in, const int* in_sizes, int n_in,
                              void* d_out, int out_size, void* d_ws, size_t ws_size,
                              hipStream_t stream) {
  const float* feat = (const float*)d_in[0];
  const int2* adj = (const int2*)d_in[1];
  const float* w_ih = (const float*)d_in[2];
  const float* w_hh = (const float*)d_in[3];
  const float* b_ih = (const float*)d_in[4];
  const float* b_hh = (const float*)d_in[5];
  const float* weight = (const float*)d_in[6];
  const float* bias = (const float*)d_in[7];
  float* out = (float*)d_out;

  size_t off = 0;
  auto take = [&](size_t bytes) -> void* {
    void* p = (char*)d_ws + off;
    off += (bytes + 255) & ~(size_t)255;
    return p;
  };
  int* deg = (int*)take((size_t)N_NODES * 4);
  int* roff = (int*)take((size_t)N_NODES * 4);
  int* cursor = (int*)take((size_t)N_NODES * 4);
  int2* csr = (int2*)take((size_t)E_EDGES * 8);
  int* sel = (int*)take((size_t)NPERMS * N_NODES * KARY * 4);
  int* lens = (int*)take((size_t)N_NODES * 4);
  short* wihb = (short*)take((size_t)4 * F * F * 2);
  short* whb = (short*)take((size_t)4 * F * F * 2);
  short* wobT = (short*)take((size_t)NOUT * 2 * F * 2);
  float4* bq = (float4*)take((size_t)F * 16);
  ushort4* xgq = (ushort4*)take((size_t)N_NODES * F * 8);
  float* hn = (float*)take((size_t)N_NODES * F * 4);
  (void)ws_size; (void)in_sizes; (void)n_in; (void)out_size;

  hipMemsetAsync(deg, 0, (size_t)N_NODES * 4, stream);
  hipMemsetAsync(cursor, 0, (size_t)N_NODES * 4, stream);

  k_hist<<<(E_EDGES + 255) / 256, 256, 0, stream>>>(adj, deg);
  k_scan<<<1, 1024, 0, stream>>>(deg, roff);
  k_scatter<<<(E_EDGES + 255) / 256, 256, 0, stream>>>(adj, roff, cursor, csr);
  k_prepw<<<4 * F * F / 256, 256, 0, stream>>>(w_ih, w_hh, b_ih, b_hh, weight, wihb, whb, wobT, bq);
  k_xg<<<N_NODES / 32, 256, 0, stream>>>(feat, wihb, bq, xgq);
  k_select<<<(N_NODES + 255) / 256, 256, 0, stream>>>(csr, roff, deg, sel, lens);
  k_lstm<<<N_NODES / LB, 256, 0, stream>>>(whb, xgq, sel, lens, hn);
  k_out<<<(N_NODES + 63) / 64, 256, 0, stream>>>(feat, hn, wobT, bias, out);
}

// Round 5
// 1491.450 us; speedup vs baseline: 4.6930x; 1.1402x over previous
//
#include <hip/hip_runtime.h>
#include <stdint.h>

#define N_NODES 100000
#define F 128
#define E_EDGES 1600000
#define KARY 8
#define NPERMS 4
#define NOUT 64

typedef __attribute__((ext_vector_type(8))) short bf16x8;
typedef __attribute__((ext_vector_type(4))) float f32x4;

// ---------------- threefry2x32 (JAX-exact, 20 rounds) ----------------
__device__ __forceinline__ uint32_t rotl32(uint32_t v, int r) {
  return (v << r) | (v >> (32 - r));
}
__device__ __forceinline__ void tf2x32(uint32_t k0, uint32_t k1, uint32_t& x0, uint32_t& x1) {
  uint32_t ks2 = k0 ^ k1 ^ 0x1BD11BDAu;
  x0 += k0; x1 += k1;
  x0 += x1; x1 = rotl32(x1,13); x1 ^= x0;
  x0 += x1; x1 = rotl32(x1,15); x1 ^= x0;
  x0 += x1; x1 = rotl32(x1,26); x1 ^= x0;
  x0 += x1; x1 = rotl32(x1, 6); x1 ^= x0;
  x0 += k1; x1 += ks2 + 1u;
  x0 += x1; x1 = rotl32(x1,17); x1 ^= x0;
  x0 += x1; x1 = rotl32(x1,29); x1 ^= x0;
  x0 += x1; x1 = rotl32(x1,16); x1 ^= x0;
  x0 += x1; x1 = rotl32(x1,24); x1 ^= x0;
  x0 += ks2; x1 += k0 + 2u;
  x0 += x1; x1 = rotl32(x1,13); x1 ^= x0;
  x0 += x1; x1 = rotl32(x1,15); x1 ^= x0;
  x0 += x1; x1 = rotl32(x1,26); x1 ^= x0;
  x0 += x1; x1 = rotl32(x1, 6); x1 ^= x0;
  x0 += k0; x1 += k1 + 3u;
  x0 += x1; x1 = rotl32(x1,17); x1 ^= x0;
  x0 += x1; x1 = rotl32(x1,29); x1 ^= x0;
  x0 += x1; x1 = rotl32(x1,16); x1 ^= x0;
  x0 += x1; x1 = rotl32(x1,24); x1 ^= x0;
  x0 += k1; x1 += ks2 + 4u;
  x0 += x1; x1 = rotl32(x1,13); x1 ^= x0;
  x0 += x1; x1 = rotl32(x1,15); x1 ^= x0;
  x0 += x1; x1 = rotl32(x1,26); x1 ^= x0;
  x0 += x1; x1 = rotl32(x1, 6); x1 ^= x0;
  x0 += ks2; x1 += k0 + 5u;
}

// bf16 helpers (RNE)
__device__ __forceinline__ unsigned short f2bf(float f) {
  uint32_t u = __float_as_uint(f);
  uint32_t r = (u + 0x7FFFu + ((u >> 16) & 1u)) >> 16;
  return (unsigned short)r;
}
__device__ __forceinline__ float ubf(uint32_t u) { return __uint_as_float(u); }

// native transcendentals: single v_exp_f32 / v_rcp_f32, no OCML fixup code.
__device__ __forceinline__ f32x4 exp2v(f32x4 x) {
  f32x4 r;
  r.x = __builtin_amdgcn_exp2f(x.x);
  r.y = __builtin_amdgcn_exp2f(x.y);
  r.z = __builtin_amdgcn_exp2f(x.z);
  r.w = __builtin_amdgcn_exp2f(x.w);
  return r;
}
__device__ __forceinline__ f32x4 rcpv(f32x4 x) {
  f32x4 r;
  r.x = __builtin_amdgcn_rcpf(x.x);
  r.y = __builtin_amdgcn_rcpf(x.y);
  r.z = __builtin_amdgcn_rcpf(x.z);
  r.w = __builtin_amdgcn_rcpf(x.w);
  return r;
}
// sigmoid(x) = rcp(1 + 2^(-x*log2e));  exact at saturation (inf->0, 0->1)
__device__ __forceinline__ f32x4 sig4(f32x4 x) {
  return rcpv(1.0f + exp2v(x * -1.44269504f));
}
// tanh(x) = 1 - 2*rcp(2^(2x*log2e) + 1)
__device__ __forceinline__ f32x4 tanh4(f32x4 x) {
  return 1.0f - 2.0f * rcpv(exp2v(x * 2.88539008f) + 1.0f);
}
__device__ __forceinline__ float sigf(float x) {
  return __builtin_amdgcn_rcpf(1.0f + __builtin_amdgcn_exp2f(x * -1.44269504f));
}

// ---------------- CSR build ----------------
__global__ void k_hist(const int2* __restrict__ adj, int* __restrict__ deg) {
  int e = blockIdx.x * blockDim.x + threadIdx.x;
  if (e < E_EDGES) atomicAdd(&deg[adj[e].x], 1);
}

__global__ void k_scan(const int* __restrict__ deg, int* __restrict__ roff) {
  __shared__ int sums[1024];
  const int tid = threadIdx.x;
  const int CH = (N_NODES + 1023) / 1024;  // 98
  int base = tid * CH;
  int s = 0;
  for (int i = 0; i < CH; ++i) {
    int idx = base + i;
    if (idx < N_NODES) s += deg[idx];
  }
  sums[tid] = s;
  __syncthreads();
  for (int off = 1; off < 1024; off <<= 1) {
    int v = (tid >= off) ? sums[tid - off] : 0;
    __syncthreads();
    sums[tid] += v;
    __syncthreads();
  }
  int run = sums[tid] - s;
  for (int i = 0; i < CH; ++i) {
    int idx = base + i;
    if (idx < N_NODES) { roff[idx] = run; run += deg[idx]; }
  }
}

__global__ void k_scatter(const int2* __restrict__ adj, const int* __restrict__ roff,
                          int* __restrict__ cursor, int2* __restrict__ csr) {
  int e = blockIdx.x * blockDim.x + threadIdx.x;
  if (e < E_EDGES) {
    int2 a = adj[e];
    int pos = roff[a.x] + atomicAdd(&cursor[a.x], 1);
    csr[pos] = make_int2(a.y, e);  // (dst, edge_id)
  }
}

// ---------------- top-8 selection, 4 perms fused (JAX lexsort-exact) --------
__global__ void k_select(const int2* __restrict__ csr, const int* __restrict__ roff,
                         const int* __restrict__ deg, int* __restrict__ sel,
                         int* __restrict__ lens) {
  int n = blockIdx.x * blockDim.x + threadIdx.x;
  if (n >= N_NODES) return;
  uint32_t pk0[NPERMS], pk1[NPERMS];
#pragma unroll
  for (int p = 0; p < NPERMS; ++p) {
    uint32_t a = 0u, b = (uint32_t)p;
    tf2x32(0u, 42u, a, b);
    pk0[p] = a; pk1[p] = b;
  }
  int off = roff[n], d = deg[n];
  unsigned long long key[NPERMS][KARY];
  int nbr[NPERMS][KARY];
#pragma unroll
  for (int p = 0; p < NPERMS; ++p)
#pragma unroll
    for (int i = 0; i < KARY; ++i) { key[p][i] = ~0ULL; nbr[p][i] = -1; }
  for (int e = 0; e < d; ++e) {
    int2 ent = csr[off + e];
#pragma unroll
    for (int p = 0; p < NPERMS; ++p) {
      uint32_t x0 = 0u, x1 = (uint32_t)ent.y;
      tf2x32(pk0[p], pk1[p], x0, x1);
      uint32_t bits = x0 ^ x1;
      unsigned long long k = ((unsigned long long)(bits >> 9) << 21) | (unsigned)ent.y;
      if (k < key[p][KARY - 1]) {
        key[p][KARY - 1] = k; nbr[p][KARY - 1] = ent.x;
#pragma unroll
        for (int s = KARY - 1; s >= 1; --s) {
          if (key[p][s] < key[p][s - 1]) {
            unsigned long long tk = key[p][s]; key[p][s] = key[p][s - 1]; key[p][s - 1] = tk;
            int tn = nbr[p][s]; nbr[p][s] = nbr[p][s - 1]; nbr[p][s - 1] = tn;
          }
        }
      }
    }
  }
  int L = d < KARY ? d : KARY;
  lens[n] = L;
#pragma unroll
  for (int p = 0; p < NPERMS; ++p)
#pragma unroll
    for (int t = 0; t < KARY; ++t)
      sel[((size_t)p * N_NODES + n) * KARY + t] = (t < L) ? nbr[p][t] : -1;
}

// ---------------- weight prep (all bf16 casts + bias quads) ----------------
__global__ void k_prepw(const float* __restrict__ w_ih, const float* __restrict__ w_hh,
                        const float* __restrict__ b_ih, const float* __restrict__ b_hh,
                        const float* __restrict__ weight,
                        short* __restrict__ wihb, short* __restrict__ whb,
                        short* __restrict__ wobT, float4* __restrict__ bq) {
  int t = blockIdx.x * blockDim.x + threadIdx.x;  // 0 .. 65535
  wihb[t] = (short)f2bf(w_ih[t]);
  whb[t] = (short)f2bf(w_hh[t]);
  if (t < 2 * F * NOUT) {
    int n = t & 63, k = t >> 6;
    wobT[n * 256 + k] = (short)f2bf(weight[k * NOUT + n]);
  }
  if (t < F)
    bq[t] = make_float4(b_ih[t] + b_hh[t], b_ih[F + t] + b_hh[F + t],
                        b_ih[2 * F + t] + b_hh[2 * F + t], b_ih[3 * F + t] + b_hh[3 * F + t]);
}

#define HS_LD 136  // 128 + 8 pad shorts

// ---------------- x-side gates via MFMA: 32 nodes/block ----------------
__global__ __launch_bounds__(256) void k_xg(const float* __restrict__ feat,
                                            const short* __restrict__ wihb,
                                            const float4* __restrict__ bq,
                                            ushort4* __restrict__ xgq) {
  __shared__ short as_[32 * HS_LD];
  const int tid = threadIdx.x;
  const int w = tid >> 6, l = tid & 63;
  const int l15 = l & 15, q = l >> 4;
  const int nb = blockIdx.x * 32;
#pragma unroll
  for (int i = 0; i < 4; ++i) {
    int idx = tid + i * 256;  // 1024 float4 = 32 rows x 128 cols
    int row = idx >> 5, c4 = (idx & 31) * 4;
    float4 v = *(const float4*)&feat[(size_t)(nb + row) * F + c4];
    ushort4 s;
    s.x = f2bf(v.x); s.y = f2bf(v.y); s.z = f2bf(v.z); s.w = f2bf(v.w);
    *(ushort4*)&as_[row * HS_LD + c4] = s;
  }
  __syncthreads();

  f32x4 acc[2][2][4];
#pragma unroll
  for (int mt = 0; mt < 2; ++mt)
#pragma unroll
    for (int ft = 0; ft < 2; ++ft)
#pragma unroll
      for (int g4 = 0; g4 < 4; ++g4) acc[mt][ft][g4] = (f32x4){0.f, 0.f, 0.f, 0.f};

  const short* ab = as_ + l15 * HS_LD + q * 8;
#pragma unroll
  for (int kt = 0; kt < 4; ++kt) {
    bf16x8 a0 = *(const bf16x8*)(ab + kt * 32);
    bf16x8 a1 = *(const bf16x8*)(ab + 16 * HS_LD + kt * 32);
#pragma unroll
    for (int g4 = 0; g4 < 4; ++g4)
#pragma unroll
      for (int ft = 0; ft < 2; ++ft) {
        bf16x8 b = *(const bf16x8*)(wihb + (size_t)(g4 * 128 + 16 * ft + 32 * w + l15) * F + q * 8 + kt * 32);
        acc[0][ft][g4] = __builtin_amdgcn_mfma_f32_16x16x32_bf16(a0, b, acc[0][ft][g4], 0, 0, 0);
        acc[1][ft][g4] = __builtin_amdgcn_mfma_f32_16x16x32_bf16(a1, b, acc[1][ft][g4], 0, 0, 0);
      }
  }
#pragma unroll
  for (int mt = 0; mt < 2; ++mt)
#pragma unroll
    for (int ft = 0; ft < 2; ++ft) {
      int fi = 32 * w + 16 * ft + l15;
      float4 bb = bq[fi];
#pragma unroll
      for (int r = 0; r < 4; ++r) {
        int node = nb + mt * 16 + q * 4 + r;
        ushort4 o;
        o.x = f2bf(acc[mt][ft][0][r] + bb.x);
        o.y = f2bf(acc[mt][ft][1][r] + bb.y);
        o.z = f2bf(acc[mt][ft][2][r] + bb.z);
        o.w = f2bf(acc[mt][ft][3][r] + bb.w);
        xgq[(size_t)node * F + fi] = o;
      }
    }
}

// ---------------- fused LSTM via MFMA, B register-persistent ----------------
// M=32 seqs (8 nodes x 4 perms), N=512 gates, K=128. Wave w owns fi slice
// [32w,32w+32). xg gathers for step t prefetched before the MFMA phase.
// Epilogue vectorized over r (the 4 perms of one node) -> v_pk_*_f32.
#define LB 8
__global__ __launch_bounds__(256, 2) void k_lstm(const short* __restrict__ whb,
                                                 const ushort4* __restrict__ xgq,
                                                 const int* __restrict__ sel,
                                                 const int* __restrict__ lens,
                                                 float* __restrict__ hneigh) {
  __shared__ short hs[32 * HS_LD];   // 8704 B
  __shared__ int sel_l[32][9];
  const int tid = threadIdx.x;
  const int w = tid >> 6;
  const int l = tid & 63;
  const int l15 = l & 15, q = l >> 4;
  const int nb = blockIdx.x * LB;
  const char* xgb = (const char*)xgq;
  const int fi8 = (32 * w + l15) * 8;  // byte offset of this lane's ft=0 quad

  {
    int m = tid >> 3, t = tid & 7;
    int node = nb + (m >> 2), p = m & 3;
    sel_l[m][t] = sel[((size_t)p * N_NODES + node) * KARY + t];
  }
  {
    int* h32 = (int*)hs;
    for (int i = tid; i < 32 * HS_LD / 2; i += 256) h32[i] = 0;
  }
  uint32_t lp = 0;
#pragma unroll
  for (int i = 0; i < 8; ++i) lp |= (uint32_t)lens[nb + i] << (4 * i);

  // persistent B: breg[kt][g4][ft]  (128 VGPRs)
  bf16x8 breg[4][4][2];
#pragma unroll
  for (int kt = 0; kt < 4; ++kt)
#pragma unroll
    for (int g4 = 0; g4 < 4; ++g4)
#pragma unroll
      for (int ft = 0; ft < 2; ++ft)
        breg[kt][g4][ft] = *(const bf16x8*)(whb + (size_t)(g4 * 128 + 16 * ft + 32 * w + l15) * F + q * 8 + kt * 32);

  const short* abase = hs + l15 * HS_LD + q * 8;

  f32x4 cst[2][2];
#pragma unroll
  for (int mt = 0; mt < 2; ++mt)
#pragma unroll
    for (int ft = 0; ft < 2; ++ft) cst[mt][ft] = (f32x4){0.f, 0.f, 0.f, 0.f};

  __syncthreads();

  for (int t = 0; t < KARY; ++t) {
    // ---- prefetch this step's xg quads; latency hides under the MFMA phase
    uint2 xr[2][4][2];  // [mt][r][ft]: (i|f<<16, g|o<<16)
#pragma unroll
    for (int mt = 0; mt < 2; ++mt)
#pragma unroll
      for (int r = 0; r < 4; ++r) {
        int seq = mt * 16 + q * 4 + r;
        int v = sel_l[seq][t];
        v = v < 0 ? 0 : v;
        int off = (v << 10) + fi8;
        xr[mt][r][0] = *(const uint2*)(xgb + off);
        xr[mt][r][1] = *(const uint2*)(xgb + off + 128);
      }

    // ---- MFMA phase
    f32x4 acc[2][2][4];
#pragma unroll
    for (int mt = 0; mt < 2; ++mt)
#pragma unroll
      for (int ft = 0; ft < 2; ++ft)
#pragma unroll
        for (int g4 = 0; g4 < 4; ++g4) acc[mt][ft][g4] = (f32x4){0.f, 0.f, 0.f, 0.f};

#pragma unroll
    for (int kt = 0; kt < 4; ++kt) {
      bf16x8 a0 = *(const bf16x8*)(abase + 0 * 16 * HS_LD + kt * 32);
      bf16x8 a1 = *(const bf16x8*)(abase + 1 * 16 * HS_LD + kt * 32);
#pragma unroll
      for (int g4 = 0; g4 < 4; ++g4)
#pragma unroll
        for (int ft = 0; ft < 2; ++ft) {
          acc[0][ft][g4] = __builtin_amdgcn_mfma_f32_16x16x32_bf16(a0, breg[kt][g4][ft], acc[0][ft][g4], 0, 0, 0);
          acc[1][ft][g4] = __builtin_amdgcn_mfma_f32_16x16x32_bf16(a1, breg[kt][g4][ft], acc[1][ft][g4], 0, 0, 0);
        }
    }
    __syncthreads();  // all hs reads done before epilogue writes

    // ---- epilogue, vectorized over r (4 perms of one node; `live` uniform)
#pragma unroll
    for (int mt = 0; mt < 2; ++mt) {
      int len = (lp >> (4 * (mt * 4 + q))) & 15;
      bool live = t < len;
#pragma unroll
      for (int ft = 0; ft < 2; ++ft) {
        f32x4 xi, xf, xg_, xo;
#pragma unroll
        for (int r = 0; r < 4; ++r) {
          uint2 x = xr[mt][r][ft];
          xi[r] = ubf(x.x << 16);
          xf[r] = ubf(x.x & 0xffff0000u);
          xg_[r] = ubf(x.y << 16);
          xo[r] = ubf(x.y & 0xffff0000u);
        }
        f32x4 ii = sig4(acc[mt][ft][0] + xi);
        f32x4 ff = sig4(acc[mt][ft][1] + xf);
        f32x4 gg = tanh4(acc[mt][ft][2] + xg_);
        f32x4 oo = sig4(acc[mt][ft][3] + xo);
        f32x4 cn = ff * cst[mt][ft] + ii * gg;
        if (live) {
          cst[mt][ft] = cn;
          f32x4 hh = oo * tanh4(cn);
          int base = (mt * 16 + q * 4) * HS_LD + 32 * w + 16 * ft + l15;
#pragma unroll
          for (int r = 0; r < 4; ++r)
            hs[base + r * HS_LD] = (short)f2bf(hh[r]);
        }
      }
    }
    __syncthreads();
  }

#pragma unroll
  for (int mt = 0; mt < 2; ++mt) {
    int node = nb + mt * 4 + q;
#pragma unroll
    for (int ft = 0; ft < 2; ++ft) {
      int fi = 32 * w + 16 * ft + l15;
      f32x4 cc = cst[mt][ft];
      hneigh[(size_t)node * F + fi] = (cc.x + cc.y + cc.z + cc.w) * 0.25f;
    }
  }
}

// ---------------- head via MFMA: 64 nodes/block, N=64, K=256 ----------------
#define OS_LD 264  // 256 + 8 pad shorts
__global__ __launch_bounds__(256) void k_out(const float* __restrict__ feat,
                                             const float* __restrict__ hn,
                                             const short* __restrict__ wobT,
                                             const float* __restrict__ bias,
                                             float* __restrict__ out) {
  __shared__ short as_[64 * OS_LD];  // 33792 B
  const int tid = threadIdx.x;
  const int w = tid >> 6, l = tid & 63;
  const int l15 = l & 15, q = l >> 4;
  const int nb = blockIdx.x * 64;
#pragma unroll
  for (int i = 0; i < 16; ++i) {
    int idx = tid + i * 256;  // 4096 float4 = 64 rows x 256 cols
    int row = idx >> 6, c4 = (idx & 63) * 4;
    int node = nb + row;
    if (node > N_NODES - 1) node = N_NODES - 1;
    float4 v = (c4 < 128) ? *(const float4*)&feat[(size_t)node * F + c4]
                          : *(const float4*)&hn[(size_t)node * F + (c4 - 128)];
    ushort4 s;
    s.x = f2bf(v.x); s.y = f2bf(v.y); s.z = f2bf(v.z); s.w = f2bf(v.w);
    *(ushort4*)&as_[row * OS_LD + c4] = s;
  }
  __syncthreads();

  f32x4 acc[4];
#pragma unroll
  for (int nt = 0; nt < 4; ++nt) acc[nt] = (f32x4){0.f, 0.f, 0.f, 0.f};

  const short* ab = as_ + (w * 16 + l15) * OS_LD + q * 8;
#pragma unroll
  for (int kt = 0; kt < 8; ++kt) {
    bf16x8 a = *(const bf16x8*)(ab + kt * 32);
#pragma unroll
    for (int nt = 0; nt < 4; ++nt) {
      bf16x8 b = *(const bf16x8*)(wobT + (size_t)(nt * 16 + l15) * 256 + q * 8 + kt * 32);
      acc[nt] = __builtin_amdgcn_mfma_f32_16x16x32_bf16(a, b, acc[nt], 0, 0, 0);
    }
  }
#pragma unroll
  for (int nt = 0; nt < 4; ++nt) {
    int col = nt * 16 + l15;
    float bb = bias[col];
#pragma unroll
    for (int r = 0; r < 4; ++r) {
      int node = nb + w * 16 + q * 4 + r;
      if (node < N_NODES)
        out[(size_t)node * NOUT + col] = sigf(acc[nt][r] + bb);
    }
  }
}

extern "C" void kernel_launch(void* const* d_in, const int* in_sizes, int n_in,
                              void* d_out, int out_size, void* d_ws, size_t ws_size,
                              hipStream_t stream) {
  const float* feat = (const float*)d_in[0];
  const int2* adj = (const int2*)d_in[1];
  const float* w_ih = (const float*)d_in[2];
  const float* w_hh = (const float*)d_in[3];
  const float* b_ih = (const float*)d_in[4];
  const float* b_hh = (const float*)d_in[5];
  const float* weight = (const float*)d_in[6];
  const float* bias = (const float*)d_in[7];
  float* out = (float*)d_out;

  size_t off = 0;
  auto take = [&](size_t bytes) -> void* {
    void* p = (char*)d_ws + off;
    off += (bytes + 255) & ~(size_t)255;
    return p;
  };
  int* deg = (int*)take((size_t)N_NODES * 4);
  int* roff = (int*)take((size_t)N_NODES * 4);
  int* cursor = (int*)take((size_t)N_NODES * 4);
  int2* csr = (int2*)take((size_t)E_EDGES * 8);
  int* sel = (int*)take((size_t)NPERMS * N_NODES * KARY * 4);
  int* lens = (int*)take((size_t)N_NODES * 4);
  short* wihb = (short*)take((size_t)4 * F * F * 2);
  short* whb = (short*)take((size_t)4 * F * F * 2);
  short* wobT = (short*)take((size_t)NOUT * 2 * F * 2);
  float4* bq = (float4*)take((size_t)F * 16);
  ushort4* xgq = (ushort4*)take((size_t)N_NODES * F * 8);
  float* hn = (float*)take((size_t)N_NODES * F * 4);
  (void)ws_size; (void)in_sizes; (void)n_in; (void)out_size;

  hipMemsetAsync(deg, 0, (size_t)N_NODES * 4, stream);
  hipMemsetAsync(cursor, 0, (size_t)N_NODES * 4, stream);

  k_hist<<<(E_EDGES + 255) / 256, 256, 0, stream>>>(adj, deg);
  k_scan<<<1, 1024, 0, stream>>>(deg, roff);
  k_scatter<<<(E_EDGES + 255) / 256, 256, 0, stream>>>(adj, roff, cursor, csr);
  k_prepw<<<4 * F * F / 256, 256, 0, stream>>>(w_ih, w_hh, b_ih, b_hh, weight, wihb, whb, wobT, bq);
  k_xg<<<N_NODES / 32, 256, 0, stream>>>(feat, wihb, bq, xgq);
  k_select<<<(N_NODES + 255) / 256, 256, 0, stream>>>(csr, roff, deg, sel, lens);
  k_lstm<<<N_NODES / LB, 256, 0, stream>>>(whb, xgq, sel, lens, hn);
  k_out<<<(N_NODES + 63) / 64, 256, 0, stream>>>(feat, hn, wobT, bias, out);
}